// Round 10
// baseline (175.964 us; speedup 1.0000x reference)
//
#include <hip/hip_runtime.h>
#include <math.h>

#define MQ 1000
#define PI_F 3.14159265358979323846f
#define EPSF 1e-12f
#define DYF  ((float)(0.998/999.0))   // main y-grid step
#define DY2F ((float)(0.999/999.0))   // disconnected y2-grid step (= 0.001)

// fast HW approx ops (v_rcp_f32 / v_rsq_f32 / v_sqrt_f32, ~1 ulp)
__device__ __forceinline__ float frcp(float x)  { return __builtin_amdgcn_rcpf(x); }
__device__ __forceinline__ float frsq(float x)  { return __builtin_amdgcn_rsqf(x); }
__device__ __forceinline__ float fsqrt(float x) { return __builtin_amdgcn_sqrtf(x); }

// ws layout: [0]=zs_max [1]=L_max [2]=zs_crit [3]=L_crit

// ---------------------------------------------------------------------------
// f(z) = 1 + q1 z + q2 z^2 + q3 z^3 + (q4 + cf4 ln z) z^4
// s(z) = 1 + e1 z + e2 z^2 + e3 z^3 + e4 z^4 ;  df = 4(f - s)/z
// eval_b_ = P(z)^2, P = 1 + b0 z + b1 z^2 + p3 z^3, p3 = a0+a1-b0-b1
// g = P^2/(1-z^4);  z dg/g = 2 z P'/P + 4 z^4/(1-z^4);  sqrt(g) = P rsqrt(1-z^4)
// ---------------------------------------------------------------------------
struct Co {
    float q1, q2, q3, q4, cf4;
    float e1, e2, e3, e4;
    float b0, b1, p3;
    float coef;
};

__device__ __forceinline__ Co make_co(const float* a, const float* b, const float* lc) {
    Co c;
    float a0 = a[0], a1 = a[1];
    float cf1 = -8.f * a0 / 3.f;
    float cf2 = -2.f * (2.f * a1 + a0 * a0);
    float cf3 = -8.f * a0 * a1;
    c.cf4 = -4.f * a1 * a1;
    c.q1 = -cf1; c.q2 = -cf2; c.q3 = -cf3; c.q4 = cf1 + cf2 + cf3 - 1.f;
    c.e1 = 2.f * a0;
    c.e2 = 2.f * a1 + a0 * a0;
    c.e3 = 2.f * a0 * a1;
    c.e4 = a1 * a1;
    c.b0 = b[0]; c.b1 = b[1];
    c.p3 = a0 + a1 - b[0] - b[1];
    c.coef = expf(lc[0]);
    return c;
}

struct Uni { float zs, fs, rfs, A4; };

__device__ __forceinline__ Uni make_uni(const Co& c, float zs) {
    Uni U; U.zs = zs;
    float z = zs;
    float lg = __logf(z);
    float t4 = c.q4 + c.cf4 * lg;
    float fz = 1.f + z * (c.q1 + z * (c.q2 + z * (c.q3 + z * t4)));
    float s  = 1.f + z * (c.e1 + z * (c.e2 + z * (c.e3 + z * c.e4)));
    U.fs = fz;
    U.rfs = frcp(fz);
    float dfs = 4.f * (fz - s) * frcp(z);
    U.A4 = zs * dfs * U.rfs - 2.f;     // (zs dfs/fs + 2) - 4
    return U;
}

// L and dL integrands at one point; y and u = 1-y^2 passed in.
__device__ __forceinline__ void point_LdL(const Co& c, const Uni& U,
                                          float y, float u,
                                          float& iL, float& iD) {
    float u2  = u * u;
    float ru2 = frcp(u2);
    float ru4 = ru2 * ru2;
    float z  = U.zs * u;
    float z2 = z * z, z4 = z2 * z2;
    float lg = __logf(z);
    float t4 = c.q4 + c.cf4 * lg;
    float fz = 1.f + z * (c.q1 + z * (c.q2 + z * (c.q3 + z * t4)));
    float s  = 1.f + z * (c.e1 + z * (c.e2 + z * (c.e3 + z * c.e4)));
    float P  = 1.f + z * (c.b0 + z * (c.b1 + z * c.p3));
    float dP = c.b0 + z * (2.f * c.b1 + z * (3.f * c.p3));
    float D  = 1.f - z4;
    float rsqD = frsq(D);
    float rcpD = rsqD * rsqD;
    float rcpP = frcp(P);
    float zdgg = 2.f * z * dP * rcpP + 4.f * z4 * rcpD;   // z dg / g
    float F4 = fz * U.rfs * ru4;                          // r4 * f/fs
    float S4 = s  * U.rfs * ru4;
    float den = fmaxf(F4 - 1.f, EPSF);                    // argL == dL denominator
    float rs  = frsq(den);
    float sqg = P * rsqD;                                 // sqrt(g)
    float t1  = sqg * rs;
    iL = t1 * y;
    float t = F4 * (U.A4 + zdgg) + 4.f * S4 - 2.f - zdgg;
    float rs2 = rs * rs;
    iD = t * (2.f * y) * (t1 * rs2);                      // sqrt(1-z/zs) = y
}

// connected-V integrand
__device__ __forceinline__ float point_Vc(const Co& c, const Uni& U,
                                          float y, float u) {
    float u2  = u * u;
    float u4  = u2 * u2;
    float ru2 = frcp(u2);                                 // 1/w
    float z  = U.zs * u;
    float z2 = z * z, z4 = z2 * z2;
    float lg = __logf(z);
    float t4 = c.q4 + c.cf4 * lg;
    float fz = 1.f + z * (c.q1 + z * (c.q2 + z * (c.q3 + z * t4)));
    float P  = 1.f + z * (c.b0 + z * (c.b1 + z * c.p3));
    float D  = 1.f - z4;
    float rsqD = frsq(D);
    float rcpD = rsqD * rsqD;
    float fg = fz * P * P * rcpD;
    float sqfg = fsqrt(fmaxf(fg, EPSF));
    float rfz = frcp(fz);
    float arg = fmaxf(1.f - u4 * U.fs * rfz, EPSF);       // 1 - w^2/fof
    float t = frsq(arg) - 1.f;
    return sqfg * ru2 * t * y;
}

// disconnected-V integrand on the y2 grid
__device__ __forceinline__ float point_Vd(const Co& c, const Uni& U, float y2) {
    float z  = 1.f - (1.f - U.zs) * y2;
    float z2 = z * z, z4 = z2 * z2;
    float lg = __logf(z);
    float t4 = c.q4 + c.cf4 * lg;
    float fz = 1.f + z * (c.q1 + z * (c.q2 + z * (c.q3 + z * t4)));
    float P  = 1.f + z * (c.b0 + z * (c.b1 + z * c.p3));
    float D  = 1.f - z4;
    float rsqD = frsq(D);
    float fg = fz * P * P * (rsqD * rsqD);
    float sq = fsqrt(fmaxf(fg, EPSF));
    float rz = frcp(z);
    return sq * rz * rz;
}

// trapz over extended grid yy=[0, y..., 1], ii=[v0, integ..., 0]
__device__ __forceinline__ float trapz_ext(float S, float i0, float i1, float iN) {
    float slope = (i1 - i0) * frcp(DYF);
    float v0 = i0 - slope * 0.001f;
    float yLast = 0.001f + 999.f * DYF;
    return DYF * (S - 0.5f * (i0 + iN))
         + 0.5f * (v0 + i0) * 0.001f
         + 0.5f * iN * (1.f - yLast);
}

__device__ __forceinline__ float trapz_d(float S, float q0, float qN) {
    return 0.5f * (1.f + q0) * 0.001f + DY2F * (S - 0.5f * (q0 + qN));
}

// ---------------------------------------------------------------------------
// Kernel 1: root searches by TRISECTION with both candidates evaluated
// concurrently: 1024 threads = 2 candidates x 512 threads x 2 points.
// (unchanged from R9)
// ---------------------------------------------------------------------------
__global__ __launch_bounds__(1024) void solve_scalars_kernel(
        const float* a, const float* b, const float* lc, float* ws) {
    __shared__ float pA[16], pB[16], spec[10];
    Co c = make_co(a, b, lc);
    int t = threadIdx.x;
    int lane = t & 63, w = t >> 6;
    int cnd = t >> 9;          // 0 or 1
    int local = t & 511;
    float y0 = fmaf((float)local, DYF, 0.001f);
    float u0 = 1.f - y0 * y0;
    float y1 = fmaf((float)(local + 512), DYF, 0.001f);
    float u1 = 1.f - y1 * y1;
    bool has2 = (local < 488);          // local+512 < 1000
    float y2a = fmaf((float)local, DY2F, 0.001f);
    float y2b = fmaf((float)(local + 512), DY2F, 0.001f);

    // --- trisection 1: root of dL on [0.001, 0.999], 7 rounds ---
    float lo = 0.001f, hi = 0.999f;
    for (int it = 0; it < 7; ++it) {
        float third = (hi - lo) * (1.f / 3.f);
        float m = fmaf((float)(cnd + 1), third, lo);
        Uni U = make_uni(c, m);
        float iL0, iD0, iL1, iD1 = 0.f;
        point_LdL(c, U, y0, u0, iL0, iD0);
        float sD = iD0;
        if (has2) { point_LdL(c, U, y1, u1, iL1, iD1); sD += iD1; }
#pragma unroll
        for (int o = 32; o > 0; o >>= 1) sD += __shfl_xor(sD, o, 64);
        if (lane == 0) pB[w] = sD;
        if (local == 0)   spec[cnd * 3 + 0] = iD0;
        if (local == 1)   spec[cnd * 3 + 1] = iD0;
        if (local == 487) spec[cnd * 3 + 2] = iD1;
        __syncthreads();
        float SD0 = 0.f, SD1 = 0.f;
#pragma unroll
        for (int i = 0; i < 8; ++i) { SD0 += pB[i]; SD1 += pB[8 + i]; }
        float dL1 = trapz_ext(SD0, spec[0], spec[1], spec[2]) / PI_F;
        float dL2 = trapz_ext(SD1, spec[3], spec[4], spec[5]) / PI_F;
        __syncthreads();
        float m1 = fmaf(1.f, third, lo), m2 = fmaf(2.f, third, lo);
        if (dL1 < 0.f)      { hi = m1; }
        else if (dL2 < 0.f) { lo = m1; hi = m2; }
        else                { lo = m2; }
    }
    float zs_max = 0.5f * (lo + hi);

    // --- trisection 2: root of -V on [0.001, zs_max], 9 rounds ---
    lo = 0.001f; hi = zs_max;
    for (int it = 0; it < 9; ++it) {
        float third = (hi - lo) * (1.f / 3.f);
        float m = fmaf((float)(cnd + 1), third, lo);
        Uni U = make_uni(c, m);
        float vc0 = point_Vc(c, U, y0, u0);
        float vd0 = point_Vd(c, U, y2a);
        float sc = vc0, sd = vd0;
        float vc1 = 0.f, vd1 = 0.f;
        if (has2) {
            vc1 = point_Vc(c, U, y1, u1);
            vd1 = point_Vd(c, U, y2b);
            sc += vc1; sd += vd1;
        }
#pragma unroll
        for (int o = 32; o > 0; o >>= 1) {
            sc += __shfl_xor(sc, o, 64);
            sd += __shfl_xor(sd, o, 64);
        }
        if (lane == 0) { pA[w] = sc; pB[w] = sd; }
        if (local == 0)   { spec[cnd * 5 + 0] = vc0; spec[cnd * 5 + 3] = vd0; }
        if (local == 1)   { spec[cnd * 5 + 1] = vc0; }
        if (local == 487) { spec[cnd * 5 + 2] = vc1; spec[cnd * 5 + 4] = vd1; }
        __syncthreads();
        float Sc0 = 0.f, Sd0 = 0.f, Sc1 = 0.f, Sd1 = 0.f;
#pragma unroll
        for (int i = 0; i < 8; ++i) {
            Sc0 += pA[i]; Sc1 += pA[8 + i];
            Sd0 += pB[i]; Sd1 += pB[8 + i];
        }
        float m1 = fmaf(1.f, third, lo), m2 = fmaf(2.f, third, lo);
        float V1 = c.coef * PI_F * 4.f * trapz_ext(Sc0, spec[0], spec[1], spec[2]) * frcp(m1)
                 - c.coef * PI_F * 2.f * (1.f - m1) * trapz_d(Sd0, spec[3], spec[4]);
        float V2 = c.coef * PI_F * 4.f * trapz_ext(Sc1, spec[5], spec[6], spec[7]) * frcp(m2)
                 - c.coef * PI_F * 2.f * (1.f - m2) * trapz_d(Sd1, spec[8], spec[9]);
        __syncthreads();
        if (V1 > 0.f)      { hi = m1; }          // root left of m1
        else if (V2 > 0.f) { lo = m1; hi = m2; }
        else               { lo = m2; }
    }
    float zs_crit = 0.5f * (lo + hi);

    // --- fused final pass: L(zs_max) and L(zs_crit), 1 pt/thread ---
    {
        bool act = (t < MQ);
        float y = fmaf((float)t, DYF, 0.001f);
        float u = 1.f - y * y;
        Uni Um = make_uni(c, zs_max);
        Uni Uc = make_uni(c, zs_crit);
        float lm = 0.f, lcv = 0.f, dump;
        if (act) {
            float d2;
            point_LdL(c, Um, y, u, lm, dump);
            point_LdL(c, Uc, y, u, lcv, d2);
        }
        float sm = lm, sc2 = lcv;
#pragma unroll
        for (int o = 32; o > 0; o >>= 1) {
            sm  += __shfl_xor(sm, o, 64);
            sc2 += __shfl_xor(sc2, o, 64);
        }
        if (lane == 0) { pA[w] = sm; pB[w] = sc2; }
        if (t == 0)      { spec[0] = lm; spec[3] = lcv; }
        if (t == 1)      { spec[1] = lm; spec[4] = lcv; }
        if (t == MQ - 1) { spec[2] = lm; spec[5] = lcv; }
        __syncthreads();
        if (t == 0) {
            float Sm = 0.f, Sc2 = 0.f;
#pragma unroll
            for (int i = 0; i < 16; ++i) { Sm += pA[i]; Sc2 += pB[i]; }
            float L_max  = 4.f * zs_max  * trapz_ext(Sm,  spec[0], spec[1], spec[2]) / PI_F;
            float L_crit = 4.f * zs_crit * trapz_ext(Sc2, spec[3], spec[4], spec[5]) / PI_F;
            ws[0] = zs_max; ws[1] = L_max; ws[2] = zs_crit; ws[3] = L_crit;
        }
    }
}

// ---------------------------------------------------------------------------
// Kernel 2: per-element Newton + V.  One wave per element, 16 points/lane.
// R10: HYBRID root update.  The straggler class (L_eff -> L_crit ~ L_max,
// root near zs_max where dL -> 0) makes plain Newton converge linearly at
// rate 1/2 (near-double-root regime) -> they pinned the 14-step cap on the
// critical SIMDs (R9: 68.6 us = 4 waves x 15 units).  Near the maximum,
// model L = L_max - C*(zs_max - zs)^2 and solve the model directly:
//   nzs = zs_max - |zs_max - zs| * sqrt((L_max - L_eff)/(L_max - Lz))
// which is superlinear exactly where Newton is slow.  Use it when
// Lz > 0.7*L_max (ill-conditioned regime), plain Newton otherwise.
// Cap 10 steps; best-res / stall / 2-cycle exits kept as safety.
// j = lane + 64k; j==0,1 -> k=0 lanes 0,1;  j==999 -> k=15 lane 39.
// ---------------------------------------------------------------------------
__global__ __launch_bounds__(256) void newton_v_kernel(
        const float* Ls, const float* a, const float* b, const float* lc,
        const float* ws, float* out, int B) {
    int wid = (blockIdx.x * blockDim.x + threadIdx.x) >> 6;
    int lane = threadIdx.x & 63;
    if (wid >= B) return;

    float L_crit = ws[3];
    float Lq = Ls[wid];
    if (!(Lq < L_crit)) {              // invalid row: exact 0, skip all work
        if (lane == 0) out[wid] = 0.f;
        return;
    }

    Co c = make_co(a, b, lc);
    float zs_max = ws[0], L_max = ws[1], zs_crit = ws[2];
    float L_eff = Lq;
    // chord through (0,0)-(L_crit, zs_crit); all valid L_eff lie inside it
    float zs = fminf(fmaxf(L_eff * frcp(L_crit) * zs_crit, 1e-4f), 0.9995f);
    float zs_prev = -1.f;
    float best_res = 1e30f, zs_best = zs;
    int stall = 0;

    for (int step = 0; step < 10; ++step) {
        Uni U = make_uni(c, zs);
        float sL = 0.f, sD = 0.f, l0 = 0.f, d0 = 0.f, lN = 0.f, dN = 0.f;
#pragma unroll
        for (int k = 0; k < 16; ++k) {
            if (k < 15 || lane < 40) {     // j < 1000; constant-true for k<15
                int j = lane + 64 * k;
                float y = fmaf((float)j, DYF, 0.001f);
                float u = 1.f - y * y;
                float iL, iD;
                point_LdL(c, U, y, u, iL, iD);
                sL += iL; sD += iD;
                if (k == 0)  { l0 = iL; d0 = iD; }
                if (k == 15) { lN = iL; dN = iD; }
            }
        }
#pragma unroll
        for (int o = 32; o > 0; o >>= 1) {
            sL += __shfl_xor(sL, o, 64);
            sD += __shfl_xor(sD, o, 64);
        }
        float i0 = __shfl(l0, 0, 64), i1 = __shfl(l0, 1, 64), iN = __shfl(lN, 39, 64);
        float e0 = __shfl(d0, 0, 64), e1 = __shfl(d0, 1, 64), eN = __shfl(dN, 39, 64);
        float Lz = 4.f * zs * trapz_ext(sL, i0, i1, iN) / PI_F;
        float dL = trapz_ext(sD, e0, e1, eN) / PI_F;
        float res = fabsf(Lz - L_eff);
        // residual exit: zs already solves L(zs)=L_eff to quadrature noise
        if (res <= fmaf(L_eff, 1e-5f, 1e-8f)) break;
        // slow-progress / stall exit: noise floor (safety net)
        if (res < 0.5f * best_res) {
            if (res < best_res) { best_res = res; zs_best = zs; }
            stall = 0;
        } else {
            if (res < best_res) { best_res = res; zs_best = zs; }
            if (++stall >= 2) { zs = zs_best; break; }
        }
        float nzs;
        if (Lz > 0.7f * L_max) {
            // near-extremum sqrt update (superlinear at the double-root limit)
            float rho = fmaxf(L_max - L_eff, 0.f) * frcp(fmaxf(L_max - Lz, 1e-12f));
            nzs = zs_max - fabsf(zs_max - zs) * fsqrt(rho);
        } else {
            nzs = zs - (Lz - L_eff) * frcp(dL);
        }
        nzs = fminf(fmaxf(nzs, 1e-4f), 0.9995f);
        if (fabsf(nzs - zs) <= fmaf(zs, 1e-5f, 1e-7f)) { zs = nzs; break; }
        if (nzs == zs_prev) break;                          // exact 2-cycle
        zs_prev = zs;
        zs = nzs;
    }

    // V(zs)
    Uni U = make_uni(c, zs);
    float sc = 0.f, sd = 0.f, c0 = 0.f, cN = 0.f, q0 = 0.f, qN = 0.f;
#pragma unroll
    for (int k = 0; k < 16; ++k) {
        if (k < 15 || lane < 40) {
            int j = lane + 64 * k;
            float y = fmaf((float)j, DYF, 0.001f);
            float u = 1.f - y * y;
            float vc = point_Vc(c, U, y, u);
            float y2 = fmaf((float)j, DY2F, 0.001f);
            float vd = point_Vd(c, U, y2);
            sc += vc; sd += vd;
            if (k == 0)  { c0 = vc; q0 = vd; }
            if (k == 15) { cN = vc; qN = vd; }
        }
    }
#pragma unroll
    for (int o = 32; o > 0; o >>= 1) {
        sc += __shfl_xor(sc, o, 64);
        sd += __shfl_xor(sd, o, 64);
    }
    float i0 = __shfl(c0, 0, 64), i1 = __shfl(c0, 1, 64), iN = __shfl(cN, 39, 64);
    float p0 = __shfl(q0, 0, 64), pN = __shfl(qN, 39, 64);
    float Vc = c.coef * PI_F * 4.f * trapz_ext(sc, i0, i1, iN) * frcp(zs);
    float Vd = c.coef * PI_F * 2.f * (1.f - zs) * trapz_d(sd, p0, pN);

    if (lane == 0) out[wid] = Vc - Vd;
}

// ---------------------------------------------------------------------------
extern "C" void kernel_launch(void* const* d_in, const int* in_sizes, int n_in,
                              void* d_out, int out_size, void* d_ws, size_t ws_size,
                              hipStream_t stream) {
    const float* Ls = (const float*)d_in[0];
    const float* a  = (const float*)d_in[1];
    const float* b  = (const float*)d_in[2];
    const float* lc = (const float*)d_in[3];
    float* out = (float*)d_out;
    float* ws  = (float*)d_ws;
    int B = in_sizes[0];

    solve_scalars_kernel<<<1, 1024, 0, stream>>>(a, b, lc, ws);

    int blocks = (B + 3) / 4;   // 4 waves (elements) per 256-thread block
    newton_v_kernel<<<blocks, 256, 0, stream>>>(Ls, a, b, lc, ws, out, B);
}

// Round 11
// 153.942 us; speedup vs baseline: 1.1431x; 1.1431x over previous
//
#include <hip/hip_runtime.h>
#include <math.h>

#define MQ 1000
#define PI_F 3.14159265358979323846f
#define EPSF 1e-12f
#define DYF  ((float)(0.998/999.0))   // main y-grid step
#define DY2F ((float)(0.999/999.0))   // disconnected y2-grid step (= 0.001)

// fast HW approx ops (v_rcp_f32 / v_rsq_f32 / v_sqrt_f32, ~1 ulp)
__device__ __forceinline__ float frcp(float x)  { return __builtin_amdgcn_rcpf(x); }
__device__ __forceinline__ float frsq(float x)  { return __builtin_amdgcn_rsqf(x); }
__device__ __forceinline__ float fsqrt(float x) { return __builtin_amdgcn_sqrtf(x); }

// ws layout: [0]=zs_max [1]=L_max [2]=zs_crit [3]=L_crit

// ---------------------------------------------------------------------------
// f(z) = 1 + q1 z + q2 z^2 + q3 z^3 + (q4 + cf4 ln z) z^4
// s(z) = 1 + e1 z + e2 z^2 + e3 z^3 + e4 z^4 ;  df = 4(f - s)/z
// eval_b_ = P(z)^2, P = 1 + b0 z + b1 z^2 + p3 z^3, p3 = a0+a1-b0-b1
// g = P^2/(1-z^4);  z dg/g = 2 z P'/P + 4 z^4/(1-z^4);  sqrt(g) = P rsqrt(1-z^4)
// ---------------------------------------------------------------------------
struct Co {
    float q1, q2, q3, q4, cf4;
    float e1, e2, e3, e4;
    float b0, b1, p3;
    float coef;
};

__device__ __forceinline__ Co make_co(const float* a, const float* b, const float* lc) {
    Co c;
    float a0 = a[0], a1 = a[1];
    float cf1 = -8.f * a0 / 3.f;
    float cf2 = -2.f * (2.f * a1 + a0 * a0);
    float cf3 = -8.f * a0 * a1;
    c.cf4 = -4.f * a1 * a1;
    c.q1 = -cf1; c.q2 = -cf2; c.q3 = -cf3; c.q4 = cf1 + cf2 + cf3 - 1.f;
    c.e1 = 2.f * a0;
    c.e2 = 2.f * a1 + a0 * a0;
    c.e3 = 2.f * a0 * a1;
    c.e4 = a1 * a1;
    c.b0 = b[0]; c.b1 = b[1];
    c.p3 = a0 + a1 - b[0] - b[1];
    c.coef = expf(lc[0]);
    return c;
}

struct Uni { float zs, fs, rfs, A4; };

__device__ __forceinline__ Uni make_uni(const Co& c, float zs) {
    Uni U; U.zs = zs;
    float z = zs;
    float lg = __logf(z);
    float t4 = c.q4 + c.cf4 * lg;
    float fz = 1.f + z * (c.q1 + z * (c.q2 + z * (c.q3 + z * t4)));
    float s  = 1.f + z * (c.e1 + z * (c.e2 + z * (c.e3 + z * c.e4)));
    U.fs = fz;
    U.rfs = frcp(fz);
    float dfs = 4.f * (fz - s) * frcp(z);
    U.A4 = zs * dfs * U.rfs - 2.f;     // (zs dfs/fs + 2) - 4
    return U;
}

// L and dL integrands at one point; y and u = 1-y^2 passed in.
__device__ __forceinline__ void point_LdL(const Co& c, const Uni& U,
                                          float y, float u,
                                          float& iL, float& iD) {
    float u2  = u * u;
    float ru2 = frcp(u2);
    float ru4 = ru2 * ru2;
    float z  = U.zs * u;
    float z2 = z * z, z4 = z2 * z2;
    float lg = __logf(z);
    float t4 = c.q4 + c.cf4 * lg;
    float fz = 1.f + z * (c.q1 + z * (c.q2 + z * (c.q3 + z * t4)));
    float s  = 1.f + z * (c.e1 + z * (c.e2 + z * (c.e3 + z * c.e4)));
    float P  = 1.f + z * (c.b0 + z * (c.b1 + z * c.p3));
    float dP = c.b0 + z * (2.f * c.b1 + z * (3.f * c.p3));
    float D  = 1.f - z4;
    float rsqD = frsq(D);
    float rcpD = rsqD * rsqD;
    float rcpP = frcp(P);
    float zdgg = 2.f * z * dP * rcpP + 4.f * z4 * rcpD;   // z dg / g
    float F4 = fz * U.rfs * ru4;                          // r4 * f/fs
    float S4 = s  * U.rfs * ru4;
    float den = fmaxf(F4 - 1.f, EPSF);                    // argL == dL denominator
    float rs  = frsq(den);
    float sqg = P * rsqD;                                 // sqrt(g)
    float t1  = sqg * rs;
    iL = t1 * y;
    float t = F4 * (U.A4 + zdgg) + 4.f * S4 - 2.f - zdgg;
    float rs2 = rs * rs;
    iD = t * (2.f * y) * (t1 * rs2);                      // sqrt(1-z/zs) = y
}

// connected-V integrand
__device__ __forceinline__ float point_Vc(const Co& c, const Uni& U,
                                          float y, float u) {
    float u2  = u * u;
    float u4  = u2 * u2;
    float ru2 = frcp(u2);                                 // 1/w
    float z  = U.zs * u;
    float z2 = z * z, z4 = z2 * z2;
    float lg = __logf(z);
    float t4 = c.q4 + c.cf4 * lg;
    float fz = 1.f + z * (c.q1 + z * (c.q2 + z * (c.q3 + z * t4)));
    float P  = 1.f + z * (c.b0 + z * (c.b1 + z * c.p3));
    float D  = 1.f - z4;
    float rsqD = frsq(D);
    float rcpD = rsqD * rsqD;
    float fg = fz * P * P * rcpD;
    float sqfg = fsqrt(fmaxf(fg, EPSF));
    float rfz = frcp(fz);
    float arg = fmaxf(1.f - u4 * U.fs * rfz, EPSF);       // 1 - w^2/fof
    float t = frsq(arg) - 1.f;
    return sqfg * ru2 * t * y;
}

// disconnected-V integrand on the y2 grid
__device__ __forceinline__ float point_Vd(const Co& c, const Uni& U, float y2) {
    float z  = 1.f - (1.f - U.zs) * y2;
    float z2 = z * z, z4 = z2 * z2;
    float lg = __logf(z);
    float t4 = c.q4 + c.cf4 * lg;
    float fz = 1.f + z * (c.q1 + z * (c.q2 + z * (c.q3 + z * t4)));
    float P  = 1.f + z * (c.b0 + z * (c.b1 + z * c.p3));
    float D  = 1.f - z4;
    float rsqD = frsq(D);
    float fg = fz * P * P * (rsqD * rsqD);
    float sq = fsqrt(fmaxf(fg, EPSF));
    float rz = frcp(z);
    return sq * rz * rz;
}

// trapz over extended grid yy=[0, y..., 1], ii=[v0, integ..., 0]
__device__ __forceinline__ float trapz_ext(float S, float i0, float i1, float iN) {
    float slope = (i1 - i0) * frcp(DYF);
    float v0 = i0 - slope * 0.001f;
    float yLast = 0.001f + 999.f * DYF;
    return DYF * (S - 0.5f * (i0 + iN))
         + 0.5f * (v0 + i0) * 0.001f
         + 0.5f * iN * (1.f - yLast);
}

__device__ __forceinline__ float trapz_d(float S, float q0, float qN) {
    return 0.5f * (1.f + q0) * 0.001f + DY2F * (S - 0.5f * (q0 + qN));
}

// ---------------------------------------------------------------------------
// Kernel 1: root searches by TRISECTION with both candidates evaluated
// concurrently: 1024 threads = 2 candidates x 512 threads x 2 points.
// (unchanged from R9)
// ---------------------------------------------------------------------------
__global__ __launch_bounds__(1024) void solve_scalars_kernel(
        const float* a, const float* b, const float* lc, float* ws) {
    __shared__ float pA[16], pB[16], spec[10];
    Co c = make_co(a, b, lc);
    int t = threadIdx.x;
    int lane = t & 63, w = t >> 6;
    int cnd = t >> 9;          // 0 or 1
    int local = t & 511;
    float y0 = fmaf((float)local, DYF, 0.001f);
    float u0 = 1.f - y0 * y0;
    float y1 = fmaf((float)(local + 512), DYF, 0.001f);
    float u1 = 1.f - y1 * y1;
    bool has2 = (local < 488);          // local+512 < 1000
    float y2a = fmaf((float)local, DY2F, 0.001f);
    float y2b = fmaf((float)(local + 512), DY2F, 0.001f);

    // --- trisection 1: root of dL on [0.001, 0.999], 7 rounds ---
    float lo = 0.001f, hi = 0.999f;
    for (int it = 0; it < 7; ++it) {
        float third = (hi - lo) * (1.f / 3.f);
        float m = fmaf((float)(cnd + 1), third, lo);
        Uni U = make_uni(c, m);
        float iL0, iD0, iL1, iD1 = 0.f;
        point_LdL(c, U, y0, u0, iL0, iD0);
        float sD = iD0;
        if (has2) { point_LdL(c, U, y1, u1, iL1, iD1); sD += iD1; }
#pragma unroll
        for (int o = 32; o > 0; o >>= 1) sD += __shfl_xor(sD, o, 64);
        if (lane == 0) pB[w] = sD;
        if (local == 0)   spec[cnd * 3 + 0] = iD0;
        if (local == 1)   spec[cnd * 3 + 1] = iD0;
        if (local == 487) spec[cnd * 3 + 2] = iD1;
        __syncthreads();
        float SD0 = 0.f, SD1 = 0.f;
#pragma unroll
        for (int i = 0; i < 8; ++i) { SD0 += pB[i]; SD1 += pB[8 + i]; }
        float dL1 = trapz_ext(SD0, spec[0], spec[1], spec[2]) / PI_F;
        float dL2 = trapz_ext(SD1, spec[3], spec[4], spec[5]) / PI_F;
        __syncthreads();
        float m1 = fmaf(1.f, third, lo), m2 = fmaf(2.f, third, lo);
        if (dL1 < 0.f)      { hi = m1; }
        else if (dL2 < 0.f) { lo = m1; hi = m2; }
        else                { lo = m2; }
    }
    float zs_max = 0.5f * (lo + hi);

    // --- trisection 2: root of -V on [0.001, zs_max], 9 rounds ---
    lo = 0.001f; hi = zs_max;
    for (int it = 0; it < 9; ++it) {
        float third = (hi - lo) * (1.f / 3.f);
        float m = fmaf((float)(cnd + 1), third, lo);
        Uni U = make_uni(c, m);
        float vc0 = point_Vc(c, U, y0, u0);
        float vd0 = point_Vd(c, U, y2a);
        float sc = vc0, sd = vd0;
        float vc1 = 0.f, vd1 = 0.f;
        if (has2) {
            vc1 = point_Vc(c, U, y1, u1);
            vd1 = point_Vd(c, U, y2b);
            sc += vc1; sd += vd1;
        }
#pragma unroll
        for (int o = 32; o > 0; o >>= 1) {
            sc += __shfl_xor(sc, o, 64);
            sd += __shfl_xor(sd, o, 64);
        }
        if (lane == 0) { pA[w] = sc; pB[w] = sd; }
        if (local == 0)   { spec[cnd * 5 + 0] = vc0; spec[cnd * 5 + 3] = vd0; }
        if (local == 1)   { spec[cnd * 5 + 1] = vc0; }
        if (local == 487) { spec[cnd * 5 + 2] = vc1; spec[cnd * 5 + 4] = vd1; }
        __syncthreads();
        float Sc0 = 0.f, Sd0 = 0.f, Sc1 = 0.f, Sd1 = 0.f;
#pragma unroll
        for (int i = 0; i < 8; ++i) {
            Sc0 += pA[i]; Sc1 += pA[8 + i];
            Sd0 += pB[i]; Sd1 += pB[8 + i];
        }
        float m1 = fmaf(1.f, third, lo), m2 = fmaf(2.f, third, lo);
        float V1 = c.coef * PI_F * 4.f * trapz_ext(Sc0, spec[0], spec[1], spec[2]) * frcp(m1)
                 - c.coef * PI_F * 2.f * (1.f - m1) * trapz_d(Sd0, spec[3], spec[4]);
        float V2 = c.coef * PI_F * 4.f * trapz_ext(Sc1, spec[5], spec[6], spec[7]) * frcp(m2)
                 - c.coef * PI_F * 2.f * (1.f - m2) * trapz_d(Sd1, spec[8], spec[9]);
        __syncthreads();
        if (V1 > 0.f)      { hi = m1; }          // root left of m1
        else if (V2 > 0.f) { lo = m1; hi = m2; }
        else               { lo = m2; }
    }
    float zs_crit = 0.5f * (lo + hi);

    // --- fused final pass: L(zs_max) and L(zs_crit), 1 pt/thread ---
    {
        bool act = (t < MQ);
        float y = fmaf((float)t, DYF, 0.001f);
        float u = 1.f - y * y;
        Uni Um = make_uni(c, zs_max);
        Uni Uc = make_uni(c, zs_crit);
        float lm = 0.f, lcv = 0.f, dump;
        if (act) {
            float d2;
            point_LdL(c, Um, y, u, lm, dump);
            point_LdL(c, Uc, y, u, lcv, d2);
        }
        float sm = lm, sc2 = lcv;
#pragma unroll
        for (int o = 32; o > 0; o >>= 1) {
            sm  += __shfl_xor(sm, o, 64);
            sc2 += __shfl_xor(sc2, o, 64);
        }
        if (lane == 0) { pA[w] = sm; pB[w] = sc2; }
        if (t == 0)      { spec[0] = lm; spec[3] = lcv; }
        if (t == 1)      { spec[1] = lm; spec[4] = lcv; }
        if (t == MQ - 1) { spec[2] = lm; spec[5] = lcv; }
        __syncthreads();
        if (t == 0) {
            float Sm = 0.f, Sc2 = 0.f;
#pragma unroll
            for (int i = 0; i < 16; ++i) { Sm += pA[i]; Sc2 += pB[i]; }
            float L_max  = 4.f * zs_max  * trapz_ext(Sm,  spec[0], spec[1], spec[2]) / PI_F;
            float L_crit = 4.f * zs_crit * trapz_ext(Sc2, spec[3], spec[4], spec[5]) / PI_F;
            ws[0] = zs_max; ws[1] = L_max; ws[2] = zs_crit; ws[3] = L_crit;
        }
    }
}

// ---------------------------------------------------------------------------
// Kernel 2: per-element Newton + V.  One wave per element, 16 points/lane.
// R11 = R9's plain-Newton loop (R10's hybrid update regressed and is
// reverted) with two tail fixes:
//   (1) stall progress criterion 0.5 -> 0.25: near-double-root Newton
//       converges at ratio -> exactly 1/2, which sat precisely on R9's 0.5
//       boundary and kept resetting the stall counter (stragglers ground to
//       the cap).  Quadratic convergers (ratios 0.1, 0.01, ...) still pass
//       0.25 easily; rate-1/2 convergers now stall-exit in ~2-3 steps with
//       the best-residual iterate (zs err ~1e-3 worst case -> V err a few
//       units vs threshold 318).
//   (2) hard cap 14 -> 8 (chord init + quadratic phase needs <= 5-6 steps
//       for all well-conditioned elements).
// j = lane + 64k; j==0,1 -> k=0 lanes 0,1;  j==999 -> k=15 lane 39.
// ---------------------------------------------------------------------------
__global__ __launch_bounds__(256) void newton_v_kernel(
        const float* Ls, const float* a, const float* b, const float* lc,
        const float* ws, float* out, int B) {
    int wid = (blockIdx.x * blockDim.x + threadIdx.x) >> 6;
    int lane = threadIdx.x & 63;
    if (wid >= B) return;

    float L_crit = ws[3];
    float Lq = Ls[wid];
    if (!(Lq < L_crit)) {              // invalid row: exact 0, skip all work
        if (lane == 0) out[wid] = 0.f;
        return;
    }

    Co c = make_co(a, b, lc);
    float zs_crit = ws[2];
    float L_eff = Lq;
    // chord through (0,0)-(L_crit, zs_crit); all valid L_eff lie inside it
    float zs = fminf(fmaxf(L_eff * frcp(L_crit) * zs_crit, 1e-4f), 0.9995f);
    float zs_prev = -1.f;
    float best_res = 1e30f, zs_best = zs;
    int stall = 0;

    for (int step = 0; step < 8; ++step) {
        Uni U = make_uni(c, zs);
        float sL = 0.f, sD = 0.f, l0 = 0.f, d0 = 0.f, lN = 0.f, dN = 0.f;
#pragma unroll
        for (int k = 0; k < 16; ++k) {
            if (k < 15 || lane < 40) {     // j < 1000; constant-true for k<15
                int j = lane + 64 * k;
                float y = fmaf((float)j, DYF, 0.001f);
                float u = 1.f - y * y;
                float iL, iD;
                point_LdL(c, U, y, u, iL, iD);
                sL += iL; sD += iD;
                if (k == 0)  { l0 = iL; d0 = iD; }
                if (k == 15) { lN = iL; dN = iD; }
            }
        }
#pragma unroll
        for (int o = 32; o > 0; o >>= 1) {
            sL += __shfl_xor(sL, o, 64);
            sD += __shfl_xor(sD, o, 64);
        }
        float i0 = __shfl(l0, 0, 64), i1 = __shfl(l0, 1, 64), iN = __shfl(lN, 39, 64);
        float e0 = __shfl(d0, 0, 64), e1 = __shfl(d0, 1, 64), eN = __shfl(dN, 39, 64);
        float Lz = 4.f * zs * trapz_ext(sL, i0, i1, iN) / PI_F;
        float dL = trapz_ext(sD, e0, e1, eN) / PI_F;
        float res = fabsf(Lz - L_eff);
        // residual exit: zs already solves L(zs)=L_eff to quadrature noise
        if (res <= fmaf(L_eff, 1e-5f, 1e-8f)) break;
        // stall exit: progress must beat the near-double-root rate (1/2)
        if (res < 0.25f * best_res) {
            best_res = res; zs_best = zs;
            stall = 0;
        } else {
            if (res < best_res) { best_res = res; zs_best = zs; }
            if (++stall >= 2) { zs = zs_best; break; }
        }
        float nzs = fminf(fmaxf(zs - (Lz - L_eff) * frcp(dL), 1e-4f), 0.9995f);
        if (fabsf(nzs - zs) <= fmaf(zs, 1e-5f, 1e-7f)) { zs = nzs; break; }
        if (nzs == zs_prev) break;                          // exact 2-cycle
        zs_prev = zs;
        zs = nzs;
    }

    // V(zs)
    Uni U = make_uni(c, zs);
    float sc = 0.f, sd = 0.f, c0 = 0.f, cN = 0.f, q0 = 0.f, qN = 0.f;
#pragma unroll
    for (int k = 0; k < 16; ++k) {
        if (k < 15 || lane < 40) {
            int j = lane + 64 * k;
            float y = fmaf((float)j, DYF, 0.001f);
            float u = 1.f - y * y;
            float vc = point_Vc(c, U, y, u);
            float y2 = fmaf((float)j, DY2F, 0.001f);
            float vd = point_Vd(c, U, y2);
            sc += vc; sd += vd;
            if (k == 0)  { c0 = vc; q0 = vd; }
            if (k == 15) { cN = vc; qN = vd; }
        }
    }
#pragma unroll
    for (int o = 32; o > 0; o >>= 1) {
        sc += __shfl_xor(sc, o, 64);
        sd += __shfl_xor(sd, o, 64);
    }
    float i0 = __shfl(c0, 0, 64), i1 = __shfl(c0, 1, 64), iN = __shfl(cN, 39, 64);
    float p0 = __shfl(q0, 0, 64), pN = __shfl(qN, 39, 64);
    float Vc = c.coef * PI_F * 4.f * trapz_ext(sc, i0, i1, iN) * frcp(zs);
    float Vd = c.coef * PI_F * 2.f * (1.f - zs) * trapz_d(sd, p0, pN);

    if (lane == 0) out[wid] = Vc - Vd;
}

// ---------------------------------------------------------------------------
extern "C" void kernel_launch(void* const* d_in, const int* in_sizes, int n_in,
                              void* d_out, int out_size, void* d_ws, size_t ws_size,
                              hipStream_t stream) {
    const float* Ls = (const float*)d_in[0];
    const float* a  = (const float*)d_in[1];
    const float* b  = (const float*)d_in[2];
    const float* lc = (const float*)d_in[3];
    float* out = (float*)d_out;
    float* ws  = (float*)d_ws;
    int B = in_sizes[0];

    solve_scalars_kernel<<<1, 1024, 0, stream>>>(a, b, lc, ws);

    int blocks = (B + 3) / 4;   // 4 waves (elements) per 256-thread block
    newton_v_kernel<<<blocks, 256, 0, stream>>>(Ls, a, b, lc, ws, out, B);
}

// Round 12
// 140.080 us; speedup vs baseline: 1.2562x; 1.0990x over previous
//
#include <hip/hip_runtime.h>
#include <math.h>

#define MQ 1000
#define PI_F 3.14159265358979323846f
#define EPSF 1e-12f
#define DYF  ((float)(0.998/999.0))   // main y-grid step
#define DY2F ((float)(0.999/999.0))   // disconnected y2-grid step (= 0.001)
#define NG   2048                     // scan-grid points per function
#define HG   (0.998f / (float)NG)     // scan-grid step

// fast HW approx ops (v_rcp_f32 / v_rsq_f32 / v_sqrt_f32, ~1 ulp)
__device__ __forceinline__ float frcp(float x)  { return __builtin_amdgcn_rcpf(x); }
__device__ __forceinline__ float frsq(float x)  { return __builtin_amdgcn_rsqf(x); }
__device__ __forceinline__ float fsqrt(float x) { return __builtin_amdgcn_sqrtf(x); }

// ws layout: [0]=zs_max [1]=L_max [2]=zs_crit [3]=L_crit
//            [16 .. 16+NG)      = dL grid values
//            [16+NG .. 16+2NG)  = V grid values

// ---------------------------------------------------------------------------
struct Co {
    float q1, q2, q3, q4, cf4;
    float e1, e2, e3, e4;
    float b0, b1, p3;
    float coef;
};

__device__ __forceinline__ Co make_co(const float* a, const float* b, const float* lc) {
    Co c;
    float a0 = a[0], a1 = a[1];
    float cf1 = -8.f * a0 / 3.f;
    float cf2 = -2.f * (2.f * a1 + a0 * a0);
    float cf3 = -8.f * a0 * a1;
    c.cf4 = -4.f * a1 * a1;
    c.q1 = -cf1; c.q2 = -cf2; c.q3 = -cf3; c.q4 = cf1 + cf2 + cf3 - 1.f;
    c.e1 = 2.f * a0;
    c.e2 = 2.f * a1 + a0 * a0;
    c.e3 = 2.f * a0 * a1;
    c.e4 = a1 * a1;
    c.b0 = b[0]; c.b1 = b[1];
    c.p3 = a0 + a1 - b[0] - b[1];
    c.coef = expf(lc[0]);
    return c;
}

struct Uni { float zs, fs, rfs, A4; };

__device__ __forceinline__ Uni make_uni(const Co& c, float zs) {
    Uni U; U.zs = zs;
    float z = zs;
    float lg = __logf(z);
    float t4 = c.q4 + c.cf4 * lg;
    float fz = 1.f + z * (c.q1 + z * (c.q2 + z * (c.q3 + z * t4)));
    float s  = 1.f + z * (c.e1 + z * (c.e2 + z * (c.e3 + z * c.e4)));
    U.fs = fz;
    U.rfs = frcp(fz);
    float dfs = 4.f * (fz - s) * frcp(z);
    U.A4 = zs * dfs * U.rfs - 2.f;     // (zs dfs/fs + 2) - 4
    return U;
}

__device__ __forceinline__ void point_LdL(const Co& c, const Uni& U,
                                          float y, float u,
                                          float& iL, float& iD) {
    float u2  = u * u;
    float ru2 = frcp(u2);
    float ru4 = ru2 * ru2;
    float z  = U.zs * u;
    float z2 = z * z, z4 = z2 * z2;
    float lg = __logf(z);
    float t4 = c.q4 + c.cf4 * lg;
    float fz = 1.f + z * (c.q1 + z * (c.q2 + z * (c.q3 + z * t4)));
    float s  = 1.f + z * (c.e1 + z * (c.e2 + z * (c.e3 + z * c.e4)));
    float P  = 1.f + z * (c.b0 + z * (c.b1 + z * c.p3));
    float dP = c.b0 + z * (2.f * c.b1 + z * (3.f * c.p3));
    float D  = 1.f - z4;
    float rsqD = frsq(D);
    float rcpD = rsqD * rsqD;
    float rcpP = frcp(P);
    float zdgg = 2.f * z * dP * rcpP + 4.f * z4 * rcpD;   // z dg / g
    float F4 = fz * U.rfs * ru4;                          // r4 * f/fs
    float S4 = s  * U.rfs * ru4;
    float den = fmaxf(F4 - 1.f, EPSF);
    float rs  = frsq(den);
    float sqg = P * rsqD;
    float t1  = sqg * rs;
    iL = t1 * y;
    float t = F4 * (U.A4 + zdgg) + 4.f * S4 - 2.f - zdgg;
    float rs2 = rs * rs;
    iD = t * (2.f * y) * (t1 * rs2);                      // sqrt(1-z/zs) = y
}

__device__ __forceinline__ float point_Vc(const Co& c, const Uni& U,
                                          float y, float u) {
    float u2  = u * u;
    float u4  = u2 * u2;
    float ru2 = frcp(u2);
    float z  = U.zs * u;
    float z2 = z * z, z4 = z2 * z2;
    float lg = __logf(z);
    float t4 = c.q4 + c.cf4 * lg;
    float fz = 1.f + z * (c.q1 + z * (c.q2 + z * (c.q3 + z * t4)));
    float P  = 1.f + z * (c.b0 + z * (c.b1 + z * c.p3));
    float D  = 1.f - z4;
    float rsqD = frsq(D);
    float rcpD = rsqD * rsqD;
    float fg = fz * P * P * rcpD;
    float sqfg = fsqrt(fmaxf(fg, EPSF));
    float rfz = frcp(fz);
    float arg = fmaxf(1.f - u4 * U.fs * rfz, EPSF);
    float t = frsq(arg) - 1.f;
    return sqfg * ru2 * t * y;
}

__device__ __forceinline__ float point_Vd(const Co& c, const Uni& U, float y2) {
    float z  = 1.f - (1.f - U.zs) * y2;
    float z2 = z * z, z4 = z2 * z2;
    float lg = __logf(z);
    float t4 = c.q4 + c.cf4 * lg;
    float fz = 1.f + z * (c.q1 + z * (c.q2 + z * (c.q3 + z * t4)));
    float P  = 1.f + z * (c.b0 + z * (c.b1 + z * c.p3));
    float D  = 1.f - z4;
    float rsqD = frsq(D);
    float fg = fz * P * P * (rsqD * rsqD);
    float sq = fsqrt(fmaxf(fg, EPSF));
    float rz = frcp(z);
    return sq * rz * rz;
}

__device__ __forceinline__ float trapz_ext(float S, float i0, float i1, float iN) {
    float slope = (i1 - i0) * frcp(DYF);
    float v0 = i0 - slope * 0.001f;
    float yLast = 0.001f + 999.f * DYF;
    return DYF * (S - 0.5f * (i0 + iN))
         + 0.5f * (v0 + i0) * 0.001f
         + 0.5f * iN * (1.f - yLast);
}

__device__ __forceinline__ float trapz_d(float S, float q0, float qN) {
    return 0.5f * (1.f + q0) * 0.001f + DY2F * (S - 0.5f * (q0 + qN));
}

// ---------------------------------------------------------------------------
// Wave-local quadratures (16 points/lane; j==0,1 -> k=0 lanes 0,1; j==999 ->
// k=15 lane 39).  All lanes return the same value.
// ---------------------------------------------------------------------------
__device__ __forceinline__ float wave_dL(const Co& c, const Uni& U, int lane) {
    float sD = 0.f, d0 = 0.f, dN = 0.f;
#pragma unroll
    for (int k = 0; k < 16; ++k) {
        if (k < 15 || lane < 40) {
            int j = lane + 64 * k;
            float y = fmaf((float)j, DYF, 0.001f);
            float u = 1.f - y * y;
            float iL, iD;
            point_LdL(c, U, y, u, iL, iD);
            sD += iD;
            if (k == 0)  d0 = iD;
            if (k == 15) dN = iD;
        }
    }
#pragma unroll
    for (int o = 32; o > 0; o >>= 1) sD += __shfl_xor(sD, o, 64);
    float e0 = __shfl(d0, 0, 64), e1 = __shfl(d0, 1, 64), eN = __shfl(dN, 39, 64);
    return trapz_ext(sD, e0, e1, eN) / PI_F;
}

__device__ __forceinline__ float wave_V(const Co& c, const Uni& U, int lane) {
    float sc = 0.f, sd = 0.f, c0 = 0.f, cN = 0.f, q0 = 0.f, qN = 0.f;
#pragma unroll
    for (int k = 0; k < 16; ++k) {
        if (k < 15 || lane < 40) {
            int j = lane + 64 * k;
            float y = fmaf((float)j, DYF, 0.001f);
            float u = 1.f - y * y;
            float vc = point_Vc(c, U, y, u);
            float y2 = fmaf((float)j, DY2F, 0.001f);
            float vd = point_Vd(c, U, y2);
            sc += vc; sd += vd;
            if (k == 0)  { c0 = vc; q0 = vd; }
            if (k == 15) { cN = vc; qN = vd; }
        }
    }
#pragma unroll
    for (int o = 32; o > 0; o >>= 1) {
        sc += __shfl_xor(sc, o, 64);
        sd += __shfl_xor(sd, o, 64);
    }
    float i0 = __shfl(c0, 0, 64), i1 = __shfl(c0, 1, 64), iN = __shfl(cN, 39, 64);
    float p0 = __shfl(q0, 0, 64), pN = __shfl(qN, 39, 64);
    float Vc = c.coef * PI_F * 4.f * trapz_ext(sc, i0, i1, iN) * frcp(U.zs);
    float Vd = c.coef * PI_F * 2.f * (1.f - U.zs) * trapz_d(sd, p0, pN);
    return Vc - Vd;
}

// ---------------------------------------------------------------------------
// Kernel A: parallel grid evaluation.  4096 waves; wave i<NG computes
// dL(z_i), wave i>=NG computes V(z_{i-NG}); z_i = 0.001 + (i+0.5)*HG.
// One quadrature unit of wall time instead of 16 serial rounds.
// ---------------------------------------------------------------------------
__global__ __launch_bounds__(256) void grid_eval_kernel(
        const float* a, const float* b, const float* lc, float* ws) {
    int wid = (blockIdx.x * blockDim.x + threadIdx.x) >> 6;
    int lane = threadIdx.x & 63;
    if (wid >= 2 * NG) return;
    Co c = make_co(a, b, lc);
    int i = (wid < NG) ? wid : wid - NG;
    float zq = fmaf((float)i + 0.5f, HG, 0.001f);
    Uni U = make_uni(c, zq);
    if (wid < NG) {
        float v = wave_dL(c, U, lane);
        if (lane == 0) ws[16 + i] = v;
    } else {
        float v = wave_V(c, U, lane);
        if (lane == 0) ws[16 + NG + i] = v;
    }
}

// ---------------------------------------------------------------------------
// Kernel B: crossing scan + 2 false-position rounds for zs_crit + fused
// final L(zs_max), L(zs_crit).  3 serial quadrature rounds instead of 17.
// dL crosses + -> - at zs_max (bracket h=4.9e-4; midpoint err 2.4e-4 is fine
// since dL(zs_max)=0 makes L_max quadratically insensitive).  V crosses
// - -> + at zs_crit (transversal) -> false position reaches ~1e-6 << 2e-5.
// Fallbacks preserve bisection endpoint semantics.
// ---------------------------------------------------------------------------
__global__ __launch_bounds__(1024) void refine_kernel(
        const float* a, const float* b, const float* lc, float* ws) {
    __shared__ float pA[16], pB[16], spec[6];
    __shared__ int sdl, sv;
    Co c = make_co(a, b, lc);
    int t = threadIdx.x;
    int lane = t & 63, w = t >> 6;
    const float* dLbuf = ws + 16;
    const float* Vbuf  = ws + 16 + NG;

    if (t == 0) { sdl = 1 << 30; sv = 1 << 30; }
    __syncthreads();
#pragma unroll
    for (int r = 0; r < NG / 1024; ++r) {
        int i = t + 1024 * r;
        float dcur = dLbuf[i];
        float dprev = (i > 0) ? dLbuf[i - 1] : 1.f;     // dL(lo) >= 0 invariant
        if (dcur < 0.f && dprev >= 0.f) atomicMin(&sdl, i);
        float vcur = Vbuf[i];
        float vprev = (i > 0) ? Vbuf[i - 1] : -1.f;     // V(lo) <= 0 invariant
        if (vcur > 0.f && vprev <= 0.f) atomicMin(&sv, i);
    }
    __syncthreads();
    int idl = sdl, iv = sv;

    // zs_max from dL crossing bracket (midpoint)
    float zs_max;
    if (idl >= NG) {
        zs_max = 0.999f;
    } else {
        float zhi = fmaf((float)idl + 0.5f, HG, 0.001f);
        float zlo = (idl > 0) ? zhi - HG : 0.001f;
        zs_max = 0.5f * (zlo + zhi);
    }

    // zs_crit: bracket + 2 false-position rounds (block-uniform control flow)
    float zs_crit;
    bool refine = false;
    float zlo = 0.001f, zhi = zs_max, vlo = -1.f, vhi = 1.f;
    if (iv >= NG) {
        zs_crit = zs_max;               // V never positive -> lo drifts to hi
    } else {
        zhi = fmaf((float)iv + 0.5f, HG, 0.001f);
        vhi = Vbuf[iv];
        if (iv > 0) { zlo = zhi - HG; vlo = Vbuf[iv - 1]; }
        else        { zlo = 0.001f;   vlo = -1.f; }
        if (zhi > zs_max) {
            zs_crit = zs_max;           // crossing beyond search range
        } else {
            refine = true;
            zs_crit = 0.5f * (zlo + zhi);
        }
    }
    if (refine) {
        bool act = (t < MQ);
        float y = fmaf((float)t, DYF, 0.001f);
        float u = 1.f - y * y;
        float y2 = fmaf((float)t, DY2F, 0.001f);
        for (int round = 0; round < 2; ++round) {
            float den = vhi - vlo;
            float znew = zlo - vlo * (zhi - zlo) * frcp(den);
            if (!(znew > zlo && znew < zhi)) znew = 0.5f * (zlo + zhi);
            Uni U = make_uni(c, znew);
            float vc = 0.f, vd = 0.f;
            if (act) { vc = point_Vc(c, U, y, u); vd = point_Vd(c, U, y2); }
            float sc = vc, sd = vd;
#pragma unroll
            for (int o = 32; o > 0; o >>= 1) {
                sc += __shfl_xor(sc, o, 64);
                sd += __shfl_xor(sd, o, 64);
            }
            if (lane == 0) { pA[w] = sc; pB[w] = sd; }
            if (t == 0)      { spec[0] = vc; spec[3] = vd; }
            if (t == 1)      { spec[1] = vc; }
            if (t == MQ - 1) { spec[2] = vc; spec[4] = vd; }
            __syncthreads();
            float Sc = 0.f, Sd = 0.f;
#pragma unroll
            for (int i = 0; i < 16; ++i) { Sc += pA[i]; Sd += pB[i]; }
            float Vc = c.coef * PI_F * 4.f * trapz_ext(Sc, spec[0], spec[1], spec[2]) * frcp(znew);
            float Vd = c.coef * PI_F * 2.f * (1.f - znew) * trapz_d(Sd, spec[3], spec[4]);
            float Vnew = Vc - Vd;
            __syncthreads();
            if (Vnew > 0.f) { zhi = znew; vhi = Vnew; }
            else            { zlo = znew; vlo = Vnew; }
        }
        float den = vhi - vlo;
        zs_crit = zlo - vlo * (zhi - zlo) * frcp(den);
        if (!(zs_crit > zlo && zs_crit < zhi)) zs_crit = 0.5f * (zlo + zhi);
    }

    // fused final pass: L(zs_max) and L(zs_crit), 1 pt/thread
    {
        bool act = (t < MQ);
        float y = fmaf((float)t, DYF, 0.001f);
        float u = 1.f - y * y;
        Uni Um = make_uni(c, zs_max);
        Uni Uc = make_uni(c, zs_crit);
        float lm = 0.f, lcv = 0.f;
        if (act) {
            float d1, d2;
            point_LdL(c, Um, y, u, lm, d1);
            point_LdL(c, Uc, y, u, lcv, d2);
        }
        float sm = lm, sc2 = lcv;
#pragma unroll
        for (int o = 32; o > 0; o >>= 1) {
            sm  += __shfl_xor(sm, o, 64);
            sc2 += __shfl_xor(sc2, o, 64);
        }
        if (lane == 0) { pA[w] = sm; pB[w] = sc2; }
        if (t == 0)      { spec[0] = lm; spec[3] = lcv; }
        if (t == 1)      { spec[1] = lm; spec[4] = lcv; }
        if (t == MQ - 1) { spec[2] = lm; spec[5] = lcv; }
        __syncthreads();
        if (t == 0) {
            float Sm = 0.f, Sc2 = 0.f;
#pragma unroll
            for (int i = 0; i < 16; ++i) { Sm += pA[i]; Sc2 += pB[i]; }
            float L_max  = 4.f * zs_max  * trapz_ext(Sm,  spec[0], spec[1], spec[2]) / PI_F;
            float L_crit = 4.f * zs_crit * trapz_ext(Sc2, spec[3], spec[4], spec[5]) / PI_F;
            ws[0] = zs_max; ws[1] = L_max; ws[2] = zs_crit; ws[3] = L_crit;
        }
    }
}

// ---------------------------------------------------------------------------
// Kernel C: per-element Newton + V (R11 loop, cap 8 -> 7).
// ---------------------------------------------------------------------------
__global__ __launch_bounds__(256) void newton_v_kernel(
        const float* Ls, const float* a, const float* b, const float* lc,
        const float* ws, float* out, int B) {
    int wid = (blockIdx.x * blockDim.x + threadIdx.x) >> 6;
    int lane = threadIdx.x & 63;
    if (wid >= B) return;

    float L_crit = ws[3];
    float Lq = Ls[wid];
    if (!(Lq < L_crit)) {              // invalid row: exact 0, skip all work
        if (lane == 0) out[wid] = 0.f;
        return;
    }

    Co c = make_co(a, b, lc);
    float zs_crit = ws[2];
    float L_eff = Lq;
    float zs = fminf(fmaxf(L_eff * frcp(L_crit) * zs_crit, 1e-4f), 0.9995f);
    float zs_prev = -1.f;
    float best_res = 1e30f, zs_best = zs;
    int stall = 0;

    for (int step = 0; step < 7; ++step) {
        Uni U = make_uni(c, zs);
        float sL = 0.f, sD = 0.f, l0 = 0.f, d0 = 0.f, lN = 0.f, dN = 0.f;
#pragma unroll
        for (int k = 0; k < 16; ++k) {
            if (k < 15 || lane < 40) {
                int j = lane + 64 * k;
                float y = fmaf((float)j, DYF, 0.001f);
                float u = 1.f - y * y;
                float iL, iD;
                point_LdL(c, U, y, u, iL, iD);
                sL += iL; sD += iD;
                if (k == 0)  { l0 = iL; d0 = iD; }
                if (k == 15) { lN = iL; dN = iD; }
            }
        }
#pragma unroll
        for (int o = 32; o > 0; o >>= 1) {
            sL += __shfl_xor(sL, o, 64);
            sD += __shfl_xor(sD, o, 64);
        }
        float i0 = __shfl(l0, 0, 64), i1 = __shfl(l0, 1, 64), iN = __shfl(lN, 39, 64);
        float e0 = __shfl(d0, 0, 64), e1 = __shfl(d0, 1, 64), eN = __shfl(dN, 39, 64);
        float Lz = 4.f * zs * trapz_ext(sL, i0, i1, iN) / PI_F;
        float dL = trapz_ext(sD, e0, e1, eN) / PI_F;
        float res = fabsf(Lz - L_eff);
        if (res <= fmaf(L_eff, 1e-5f, 1e-8f)) break;
        if (res < 0.25f * best_res) {
            best_res = res; zs_best = zs;
            stall = 0;
        } else {
            if (res < best_res) { best_res = res; zs_best = zs; }
            if (++stall >= 2) { zs = zs_best; break; }
        }
        float nzs = fminf(fmaxf(zs - (Lz - L_eff) * frcp(dL), 1e-4f), 0.9995f);
        if (fabsf(nzs - zs) <= fmaf(zs, 1e-5f, 1e-7f)) { zs = nzs; break; }
        if (nzs == zs_prev) break;
        zs_prev = zs;
        zs = nzs;
    }

    // V(zs)
    Uni U = make_uni(c, zs);
    float V = wave_V(c, U, lane);
    if (lane == 0) out[wid] = V;
}

// ---------------------------------------------------------------------------
extern "C" void kernel_launch(void* const* d_in, const int* in_sizes, int n_in,
                              void* d_out, int out_size, void* d_ws, size_t ws_size,
                              hipStream_t stream) {
    const float* Ls = (const float*)d_in[0];
    const float* a  = (const float*)d_in[1];
    const float* b  = (const float*)d_in[2];
    const float* lc = (const float*)d_in[3];
    float* out = (float*)d_out;
    float* ws  = (float*)d_ws;
    int B = in_sizes[0];

    int blocksA = (2 * NG * 64) / 256;       // 4096 waves
    grid_eval_kernel<<<blocksA, 256, 0, stream>>>(a, b, lc, ws);
    refine_kernel<<<1, 1024, 0, stream>>>(a, b, lc, ws);

    int blocks = (B + 3) / 4;                // 4 waves (elements) per block
    newton_v_kernel<<<blocks, 256, 0, stream>>>(Ls, a, b, lc, ws, out, B);
}

// Round 13
// 127.161 us; speedup vs baseline: 1.3838x; 1.1016x over previous
//
#include <hip/hip_runtime.h>
#include <math.h>

#define MQ 1000
#define PI_F 3.14159265358979323846f
#define EPSF 1e-12f
#define DYF  ((float)(0.998/999.0))   // main y-grid step
#define DY2F ((float)(0.999/999.0))   // disconnected y2-grid step (= 0.001)
#define NG   2048                     // scan-grid points per function
#define HG   (0.998f / (float)NG)     // scan-grid step

// fast HW approx ops (v_rcp_f32 / v_rsq_f32 / v_sqrt_f32, ~1 ulp)
__device__ __forceinline__ float frcp(float x)  { return __builtin_amdgcn_rcpf(x); }
__device__ __forceinline__ float frsq(float x)  { return __builtin_amdgcn_rsqf(x); }
__device__ __forceinline__ float fsqrt(float x) { return __builtin_amdgcn_sqrtf(x); }

// ws layout: [0]=zs_max [1]=L_max [2]=zs_crit [3]=L_crit
//            [16 .. 16+NG)      = dL grid values
//            [16+NG .. 16+2NG)  = V grid values

// ---------------------------------------------------------------------------
struct Co {
    float q1, q2, q3, q4, cf4;
    float e1, e2, e3, e4;
    float b0, b1, p3;
    float coef;
};

__device__ __forceinline__ Co make_co(const float* a, const float* b, const float* lc) {
    Co c;
    float a0 = a[0], a1 = a[1];
    float cf1 = -8.f * a0 / 3.f;
    float cf2 = -2.f * (2.f * a1 + a0 * a0);
    float cf3 = -8.f * a0 * a1;
    c.cf4 = -4.f * a1 * a1;
    c.q1 = -cf1; c.q2 = -cf2; c.q3 = -cf3; c.q4 = cf1 + cf2 + cf3 - 1.f;
    c.e1 = 2.f * a0;
    c.e2 = 2.f * a1 + a0 * a0;
    c.e3 = 2.f * a0 * a1;
    c.e4 = a1 * a1;
    c.b0 = b[0]; c.b1 = b[1];
    c.p3 = a0 + a1 - b[0] - b[1];
    c.coef = expf(lc[0]);
    return c;
}

struct Uni { float zs, fs, rfs, A4; };

__device__ __forceinline__ Uni make_uni(const Co& c, float zs) {
    Uni U; U.zs = zs;
    float z = zs;
    float lg = __logf(z);
    float t4 = c.q4 + c.cf4 * lg;
    float fz = 1.f + z * (c.q1 + z * (c.q2 + z * (c.q3 + z * t4)));
    float s  = 1.f + z * (c.e1 + z * (c.e2 + z * (c.e3 + z * c.e4)));
    U.fs = fz;
    U.rfs = frcp(fz);
    float dfs = 4.f * (fz - s) * frcp(z);
    U.A4 = zs * dfs * U.rfs - 2.f;     // (zs dfs/fs + 2) - 4
    return U;
}

__device__ __forceinline__ void point_LdL(const Co& c, const Uni& U,
                                          float y, float u,
                                          float& iL, float& iD) {
    float u2  = u * u;
    float ru2 = frcp(u2);
    float ru4 = ru2 * ru2;
    float z  = U.zs * u;
    float z2 = z * z, z4 = z2 * z2;
    float lg = __logf(z);
    float t4 = c.q4 + c.cf4 * lg;
    float fz = 1.f + z * (c.q1 + z * (c.q2 + z * (c.q3 + z * t4)));
    float s  = 1.f + z * (c.e1 + z * (c.e2 + z * (c.e3 + z * c.e4)));
    float P  = 1.f + z * (c.b0 + z * (c.b1 + z * c.p3));
    float dP = c.b0 + z * (2.f * c.b1 + z * (3.f * c.p3));
    float D  = 1.f - z4;
    float rsqD = frsq(D);
    float rcpD = rsqD * rsqD;
    float rcpP = frcp(P);
    float zdgg = 2.f * z * dP * rcpP + 4.f * z4 * rcpD;   // z dg / g
    float F4 = fz * U.rfs * ru4;                          // r4 * f/fs
    float S4 = s  * U.rfs * ru4;
    float den = fmaxf(F4 - 1.f, EPSF);
    float rs  = frsq(den);
    float sqg = P * rsqD;
    float t1  = sqg * rs;
    iL = t1 * y;
    float t = F4 * (U.A4 + zdgg) + 4.f * S4 - 2.f - zdgg;
    float rs2 = rs * rs;
    iD = t * (2.f * y) * (t1 * rs2);                      // sqrt(1-z/zs) = y
}

__device__ __forceinline__ float point_Vc(const Co& c, const Uni& U,
                                          float y, float u) {
    float u2  = u * u;
    float u4  = u2 * u2;
    float ru2 = frcp(u2);
    float z  = U.zs * u;
    float z2 = z * z, z4 = z2 * z2;
    float lg = __logf(z);
    float t4 = c.q4 + c.cf4 * lg;
    float fz = 1.f + z * (c.q1 + z * (c.q2 + z * (c.q3 + z * t4)));
    float P  = 1.f + z * (c.b0 + z * (c.b1 + z * c.p3));
    float D  = 1.f - z4;
    float rsqD = frsq(D);
    float rcpD = rsqD * rsqD;
    float fg = fz * P * P * rcpD;
    float sqfg = fsqrt(fmaxf(fg, EPSF));
    float rfz = frcp(fz);
    float arg = fmaxf(1.f - u4 * U.fs * rfz, EPSF);
    float t = frsq(arg) - 1.f;
    return sqfg * ru2 * t * y;
}

__device__ __forceinline__ float point_Vd(const Co& c, const Uni& U, float y2) {
    float z  = 1.f - (1.f - U.zs) * y2;
    float z2 = z * z, z4 = z2 * z2;
    float lg = __logf(z);
    float t4 = c.q4 + c.cf4 * lg;
    float fz = 1.f + z * (c.q1 + z * (c.q2 + z * (c.q3 + z * t4)));
    float P  = 1.f + z * (c.b0 + z * (c.b1 + z * c.p3));
    float D  = 1.f - z4;
    float rsqD = frsq(D);
    float fg = fz * P * P * (rsqD * rsqD);
    float sq = fsqrt(fmaxf(fg, EPSF));
    float rz = frcp(z);
    return sq * rz * rz;
}

__device__ __forceinline__ float trapz_ext(float S, float i0, float i1, float iN) {
    float slope = (i1 - i0) * frcp(DYF);
    float v0 = i0 - slope * 0.001f;
    float yLast = 0.001f + 999.f * DYF;
    return DYF * (S - 0.5f * (i0 + iN))
         + 0.5f * (v0 + i0) * 0.001f
         + 0.5f * iN * (1.f - yLast);
}

__device__ __forceinline__ float trapz_d(float S, float q0, float qN) {
    return 0.5f * (1.f + q0) * 0.001f + DY2F * (S - 0.5f * (q0 + qN));
}

// ---------------------------------------------------------------------------
// Wave-local quadratures (16 points/lane) for the solve path.
// ---------------------------------------------------------------------------
__device__ __forceinline__ float wave_dL(const Co& c, const Uni& U, int lane) {
    float sD = 0.f, d0 = 0.f, dN = 0.f;
#pragma unroll
    for (int k = 0; k < 16; ++k) {
        if (k < 15 || lane < 40) {
            int j = lane + 64 * k;
            float y = fmaf((float)j, DYF, 0.001f);
            float u = 1.f - y * y;
            float iL, iD;
            point_LdL(c, U, y, u, iL, iD);
            sD += iD;
            if (k == 0)  d0 = iD;
            if (k == 15) dN = iD;
        }
    }
#pragma unroll
    for (int o = 32; o > 0; o >>= 1) sD += __shfl_xor(sD, o, 64);
    float e0 = __shfl(d0, 0, 64), e1 = __shfl(d0, 1, 64), eN = __shfl(dN, 39, 64);
    return trapz_ext(sD, e0, e1, eN) / PI_F;
}

__device__ __forceinline__ float wave_V(const Co& c, const Uni& U, int lane) {
    float sc = 0.f, sd = 0.f, c0 = 0.f, cN = 0.f, q0 = 0.f, qN = 0.f;
#pragma unroll
    for (int k = 0; k < 16; ++k) {
        if (k < 15 || lane < 40) {
            int j = lane + 64 * k;
            float y = fmaf((float)j, DYF, 0.001f);
            float u = 1.f - y * y;
            float vc = point_Vc(c, U, y, u);
            float y2 = fmaf((float)j, DY2F, 0.001f);
            float vd = point_Vd(c, U, y2);
            sc += vc; sd += vd;
            if (k == 0)  { c0 = vc; q0 = vd; }
            if (k == 15) { cN = vc; qN = vd; }
        }
    }
#pragma unroll
    for (int o = 32; o > 0; o >>= 1) {
        sc += __shfl_xor(sc, o, 64);
        sd += __shfl_xor(sd, o, 64);
    }
    float i0 = __shfl(c0, 0, 64), i1 = __shfl(c0, 1, 64), iN = __shfl(cN, 39, 64);
    float p0 = __shfl(q0, 0, 64), pN = __shfl(qN, 39, 64);
    float Vc = c.coef * PI_F * 4.f * trapz_ext(sc, i0, i1, iN) * frcp(U.zs);
    float Vd = c.coef * PI_F * 2.f * (1.f - U.zs) * trapz_d(sd, p0, pN);
    return Vc - Vd;
}

// ---------------------------------------------------------------------------
// Kernel A: parallel grid evaluation (unchanged from R12).
// ---------------------------------------------------------------------------
__global__ __launch_bounds__(256) void grid_eval_kernel(
        const float* a, const float* b, const float* lc, float* ws) {
    int wid = (blockIdx.x * blockDim.x + threadIdx.x) >> 6;
    int lane = threadIdx.x & 63;
    if (wid >= 2 * NG) return;
    Co c = make_co(a, b, lc);
    int i = (wid < NG) ? wid : wid - NG;
    float zq = fmaf((float)i + 0.5f, HG, 0.001f);
    Uni U = make_uni(c, zq);
    if (wid < NG) {
        float v = wave_dL(c, U, lane);
        if (lane == 0) ws[16 + i] = v;
    } else {
        float v = wave_V(c, U, lane);
        if (lane == 0) ws[16 + NG + i] = v;
    }
}

// ---------------------------------------------------------------------------
// Kernel B: crossing scan + 2 false-position rounds (unchanged from R12).
// ---------------------------------------------------------------------------
__global__ __launch_bounds__(1024) void refine_kernel(
        const float* a, const float* b, const float* lc, float* ws) {
    __shared__ float pA[16], pB[16], spec[6];
    __shared__ int sdl, sv;
    Co c = make_co(a, b, lc);
    int t = threadIdx.x;
    int lane = t & 63, w = t >> 6;
    const float* dLbuf = ws + 16;
    const float* Vbuf  = ws + 16 + NG;

    if (t == 0) { sdl = 1 << 30; sv = 1 << 30; }
    __syncthreads();
#pragma unroll
    for (int r = 0; r < NG / 1024; ++r) {
        int i = t + 1024 * r;
        float dcur = dLbuf[i];
        float dprev = (i > 0) ? dLbuf[i - 1] : 1.f;     // dL(lo) >= 0 invariant
        if (dcur < 0.f && dprev >= 0.f) atomicMin(&sdl, i);
        float vcur = Vbuf[i];
        float vprev = (i > 0) ? Vbuf[i - 1] : -1.f;     // V(lo) <= 0 invariant
        if (vcur > 0.f && vprev <= 0.f) atomicMin(&sv, i);
    }
    __syncthreads();
    int idl = sdl, iv = sv;

    float zs_max;
    if (idl >= NG) {
        zs_max = 0.999f;
    } else {
        float zhi = fmaf((float)idl + 0.5f, HG, 0.001f);
        float zlo = (idl > 0) ? zhi - HG : 0.001f;
        zs_max = 0.5f * (zlo + zhi);
    }

    float zs_crit;
    bool refine = false;
    float zlo = 0.001f, zhi = zs_max, vlo = -1.f, vhi = 1.f;
    if (iv >= NG) {
        zs_crit = zs_max;
    } else {
        zhi = fmaf((float)iv + 0.5f, HG, 0.001f);
        vhi = Vbuf[iv];
        if (iv > 0) { zlo = zhi - HG; vlo = Vbuf[iv - 1]; }
        else        { zlo = 0.001f;   vlo = -1.f; }
        if (zhi > zs_max) {
            zs_crit = zs_max;
        } else {
            refine = true;
            zs_crit = 0.5f * (zlo + zhi);
        }
    }
    if (refine) {
        bool act = (t < MQ);
        float y = fmaf((float)t, DYF, 0.001f);
        float u = 1.f - y * y;
        float y2 = fmaf((float)t, DY2F, 0.001f);
        for (int round = 0; round < 2; ++round) {
            float den = vhi - vlo;
            float znew = zlo - vlo * (zhi - zlo) * frcp(den);
            if (!(znew > zlo && znew < zhi)) znew = 0.5f * (zlo + zhi);
            Uni U = make_uni(c, znew);
            float vc = 0.f, vd = 0.f;
            if (act) { vc = point_Vc(c, U, y, u); vd = point_Vd(c, U, y2); }
            float sc = vc, sd = vd;
#pragma unroll
            for (int o = 32; o > 0; o >>= 1) {
                sc += __shfl_xor(sc, o, 64);
                sd += __shfl_xor(sd, o, 64);
            }
            if (lane == 0) { pA[w] = sc; pB[w] = sd; }
            if (t == 0)      { spec[0] = vc; spec[3] = vd; }
            if (t == 1)      { spec[1] = vc; }
            if (t == MQ - 1) { spec[2] = vc; spec[4] = vd; }
            __syncthreads();
            float Sc = 0.f, Sd = 0.f;
#pragma unroll
            for (int i = 0; i < 16; ++i) { Sc += pA[i]; Sd += pB[i]; }
            float Vc = c.coef * PI_F * 4.f * trapz_ext(Sc, spec[0], spec[1], spec[2]) * frcp(znew);
            float Vd = c.coef * PI_F * 2.f * (1.f - znew) * trapz_d(Sd, spec[3], spec[4]);
            float Vnew = Vc - Vd;
            __syncthreads();
            if (Vnew > 0.f) { zhi = znew; vhi = Vnew; }
            else            { zlo = znew; vlo = Vnew; }
        }
        float den = vhi - vlo;
        zs_crit = zlo - vlo * (zhi - zlo) * frcp(den);
        if (!(zs_crit > zlo && zs_crit < zhi)) zs_crit = 0.5f * (zlo + zhi);
    }

    {
        bool act = (t < MQ);
        float y = fmaf((float)t, DYF, 0.001f);
        float u = 1.f - y * y;
        Uni Um = make_uni(c, zs_max);
        Uni Uc = make_uni(c, zs_crit);
        float lm = 0.f, lcv = 0.f;
        if (act) {
            float d1, d2;
            point_LdL(c, Um, y, u, lm, d1);
            point_LdL(c, Uc, y, u, lcv, d2);
        }
        float sm = lm, sc2 = lcv;
#pragma unroll
        for (int o = 32; o > 0; o >>= 1) {
            sm  += __shfl_xor(sm, o, 64);
            sc2 += __shfl_xor(sc2, o, 64);
        }
        if (lane == 0) { pA[w] = sm; pB[w] = sc2; }
        if (t == 0)      { spec[0] = lm; spec[3] = lcv; }
        if (t == 1)      { spec[1] = lm; spec[4] = lcv; }
        if (t == MQ - 1) { spec[2] = lm; spec[5] = lcv; }
        __syncthreads();
        if (t == 0) {
            float Sm = 0.f, Sc2 = 0.f;
#pragma unroll
            for (int i = 0; i < 16; ++i) { Sm += pA[i]; Sc2 += pB[i]; }
            float L_max  = 4.f * zs_max  * trapz_ext(Sm,  spec[0], spec[1], spec[2]) / PI_F;
            float L_crit = 4.f * zs_crit * trapz_ext(Sc2, spec[3], spec[4], spec[5]) / PI_F;
            ws[0] = zs_max; ws[1] = L_max; ws[2] = zs_crit; ws[3] = L_crit;
        }
    }
}

// ---------------------------------------------------------------------------
// Kernel C: per-element Newton + V.  R13: ONE BLOCK OF 128 THREADS (2 waves)
// PER ELEMENT, 8 points/lane.  R12's 69 us == critical SIMD serializing 4
// single-wave elements x 8 units x 5.2k cyc; splitting each element across
// 2 waves halves the per-unit issue on the critical path and spreads
// straggler work.  Reduction: wave shfl partials -> LDS, ONE barrier per
// step via parity double-buffering (reads of parity p and the next writes
// to p are separated by the p^1 barrier).  All exit decisions are computed
// from identical broadcast sums -> block-uniform branches.
// j = t + 128k, k<8 (k==7 -> t<104); j==0,1 -> t=0,1 (k=0); j==999 -> t=103 (k=7).
// ---------------------------------------------------------------------------
__global__ __launch_bounds__(128) void newton_v_kernel(
        const float* Ls, const float* a, const float* b, const float* lc,
        const float* ws, float* out, int B) {
    __shared__ float red[2][2][2];   // [parity][{L,D}][wave]
    __shared__ float sp[2][6];       // [parity][i0,i1,iN, d0,d1,dN]
    int wid = blockIdx.x;
    int t = threadIdx.x;
    int lane = t & 63, w = t >> 6;
    if (wid >= B) return;

    float L_crit = ws[3];
    float Lq = Ls[wid];
    if (!(Lq < L_crit)) {              // invalid row: exact 0, skip all work
        if (t == 0) out[wid] = 0.f;
        return;
    }

    Co c = make_co(a, b, lc);
    float zs_crit = ws[2];
    float L_eff = Lq;
    float zs = fminf(fmaxf(L_eff * frcp(L_crit) * zs_crit, 1e-4f), 0.9995f);
    float zs_prev = -1.f;
    float best_res = 1e30f, zs_best = zs;
    int stall = 0;
    int par = 0;

    for (int step = 0; step < 7; ++step) {
        Uni U = make_uni(c, zs);
        float sL = 0.f, sD = 0.f, l0 = 0.f, d0 = 0.f, l1 = 0.f, d1 = 0.f,
              lN = 0.f, dN = 0.f;
#pragma unroll
        for (int k = 0; k < 8; ++k) {
            if (k < 7 || t < 104) {        // j < 1000; constant-true for k<7
                int j = t + 128 * k;
                float y = fmaf((float)j, DYF, 0.001f);
                float u = 1.f - y * y;
                float iL, iD;
                point_LdL(c, U, y, u, iL, iD);
                sL += iL; sD += iD;
                if (k == 0) {
                    if (t == 0) { l0 = iL; d0 = iD; }
                    if (t == 1) { l1 = iL; d1 = iD; }
                }
                if (k == 7 && t == 103) { lN = iL; dN = iD; }
            }
        }
#pragma unroll
        for (int o = 32; o > 0; o >>= 1) {
            sL += __shfl_xor(sL, o, 64);
            sD += __shfl_xor(sD, o, 64);
        }
        if (lane == 0) { red[par][0][w] = sL; red[par][1][w] = sD; }
        if (t == 0)   { sp[par][0] = l0; sp[par][3] = d0; }
        if (t == 1)   { sp[par][1] = l1; sp[par][4] = d1; }
        if (t == 103) { sp[par][2] = lN; sp[par][5] = dN; }
        __syncthreads();
        float SL = red[par][0][0] + red[par][0][1];
        float SD = red[par][1][0] + red[par][1][1];
        float i0 = sp[par][0], i1 = sp[par][1], iN = sp[par][2];
        float e0 = sp[par][3], e1 = sp[par][4], eN = sp[par][5];
        par ^= 1;                         // next step writes the other buffer
        float Lz = 4.f * zs * trapz_ext(SL, i0, i1, iN) / PI_F;
        float dL = trapz_ext(SD, e0, e1, eN) / PI_F;
        float res = fabsf(Lz - L_eff);
        if (res <= fmaf(L_eff, 1e-5f, 1e-8f)) break;
        if (res < 0.25f * best_res) {
            best_res = res; zs_best = zs;
            stall = 0;
        } else {
            if (res < best_res) { best_res = res; zs_best = zs; }
            if (++stall >= 2) { zs = zs_best; break; }
        }
        float nzs = fminf(fmaxf(zs - (Lz - L_eff) * frcp(dL), 1e-4f), 0.9995f);
        if (fabsf(nzs - zs) <= fmaf(zs, 1e-5f, 1e-7f)) { zs = nzs; break; }
        if (nzs == zs_prev) break;
        zs_prev = zs;
        zs = nzs;
    }

    // V(zs): same 2-wave split; reuse parity buffers (barrier inside).
    Uni U = make_uni(c, zs);
    float sc = 0.f, sd = 0.f, c0 = 0.f, c1v = 0.f, cN = 0.f, q0 = 0.f, qN = 0.f;
#pragma unroll
    for (int k = 0; k < 8; ++k) {
        if (k < 7 || t < 104) {
            int j = t + 128 * k;
            float y = fmaf((float)j, DYF, 0.001f);
            float u = 1.f - y * y;
            float vc = point_Vc(c, U, y, u);
            float y2 = fmaf((float)j, DY2F, 0.001f);
            float vd = point_Vd(c, U, y2);
            sc += vc; sd += vd;
            if (k == 0) {
                if (t == 0) { c0 = vc; q0 = vd; }
                if (t == 1) { c1v = vc; }
            }
            if (k == 7 && t == 103) { cN = vc; qN = vd; }
        }
    }
#pragma unroll
    for (int o = 32; o > 0; o >>= 1) {
        sc += __shfl_xor(sc, o, 64);
        sd += __shfl_xor(sd, o, 64);
    }
    if (lane == 0) { red[par][0][w] = sc; red[par][1][w] = sd; }
    if (t == 0)   { sp[par][0] = c0; sp[par][3] = q0; }
    if (t == 1)   { sp[par][1] = c1v; }
    if (t == 103) { sp[par][2] = cN; sp[par][4] = qN; }
    __syncthreads();
    if (t == 0) {
        float Sc = red[par][0][0] + red[par][0][1];
        float Sd = red[par][1][0] + red[par][1][1];
        float Vc = c.coef * PI_F * 4.f * trapz_ext(Sc, sp[par][0], sp[par][1], sp[par][2]) * frcp(zs);
        float Vd = c.coef * PI_F * 2.f * (1.f - zs) * trapz_d(Sd, sp[par][3], sp[par][4]);
        out[wid] = Vc - Vd;
    }
}

// ---------------------------------------------------------------------------
extern "C" void kernel_launch(void* const* d_in, const int* in_sizes, int n_in,
                              void* d_out, int out_size, void* d_ws, size_t ws_size,
                              hipStream_t stream) {
    const float* Ls = (const float*)d_in[0];
    const float* a  = (const float*)d_in[1];
    const float* b  = (const float*)d_in[2];
    const float* lc = (const float*)d_in[3];
    float* out = (float*)d_out;
    float* ws  = (float*)d_ws;
    int B = in_sizes[0];

    int blocksA = (2 * NG * 64) / 256;       // 4096 waves
    grid_eval_kernel<<<blocksA, 256, 0, stream>>>(a, b, lc, ws);
    refine_kernel<<<1, 1024, 0, stream>>>(a, b, lc, ws);

    newton_v_kernel<<<B, 128, 0, stream>>>(Ls, a, b, lc, ws, out, B);
}

// Round 14
// 113.107 us; speedup vs baseline: 1.5557x; 1.1242x over previous
//
#include <hip/hip_runtime.h>
#include <math.h>

#define MQ 1000
#define PI_F 3.14159265358979323846f
#define EPSF 1e-12f
#define DYF  ((float)(0.998/999.0))   // main y-grid step
#define DY2F ((float)(0.999/999.0))   // disconnected y2-grid step (= 0.001)
#define NG   2048                     // scan-grid points per function
#define HG   (0.998f / (float)NG)     // scan-grid step

// fast HW approx ops (v_rcp_f32 / v_rsq_f32 / v_sqrt_f32, ~1 ulp)
__device__ __forceinline__ float frcp(float x)  { return __builtin_amdgcn_rcpf(x); }
__device__ __forceinline__ float frsq(float x)  { return __builtin_amdgcn_rsqf(x); }
__device__ __forceinline__ float fsqrt(float x) { return __builtin_amdgcn_sqrtf(x); }

// ws layout: [0]=zs_max [1]=L_max [2]=zs_crit [3]=L_crit [4]=table bound (idl)
//            [16 .. 16+NG)           = dL grid
//            [16+NG .. 16+2NG)       = V grid
//            [16+2NG .. 16+3NG)      = L grid (monotone for z < zs_max)
//            grid z_i = 0.001 + (i+0.5)*HG

// ---------------------------------------------------------------------------
struct Co {
    float q1, q2, q3, q4, cf4;
    float e1, e2, e3, e4;
    float b0, b1, p3;
    float coef;
};

__device__ __forceinline__ Co make_co(const float* a, const float* b, const float* lc) {
    Co c;
    float a0 = a[0], a1 = a[1];
    float cf1 = -8.f * a0 / 3.f;
    float cf2 = -2.f * (2.f * a1 + a0 * a0);
    float cf3 = -8.f * a0 * a1;
    c.cf4 = -4.f * a1 * a1;
    c.q1 = -cf1; c.q2 = -cf2; c.q3 = -cf3; c.q4 = cf1 + cf2 + cf3 - 1.f;
    c.e1 = 2.f * a0;
    c.e2 = 2.f * a1 + a0 * a0;
    c.e3 = 2.f * a0 * a1;
    c.e4 = a1 * a1;
    c.b0 = b[0]; c.b1 = b[1];
    c.p3 = a0 + a1 - b[0] - b[1];
    c.coef = expf(lc[0]);
    return c;
}

struct Uni { float zs, fs, rfs, A4; };

__device__ __forceinline__ Uni make_uni(const Co& c, float zs) {
    Uni U; U.zs = zs;
    float z = zs;
    float lg = __logf(z);
    float t4 = c.q4 + c.cf4 * lg;
    float fz = 1.f + z * (c.q1 + z * (c.q2 + z * (c.q3 + z * t4)));
    float s  = 1.f + z * (c.e1 + z * (c.e2 + z * (c.e3 + z * c.e4)));
    U.fs = fz;
    U.rfs = frcp(fz);
    float dfs = 4.f * (fz - s) * frcp(z);
    U.A4 = zs * dfs * U.rfs - 2.f;     // (zs dfs/fs + 2) - 4
    return U;
}

__device__ __forceinline__ void point_LdL(const Co& c, const Uni& U,
                                          float y, float u,
                                          float& iL, float& iD) {
    float u2  = u * u;
    float ru2 = frcp(u2);
    float ru4 = ru2 * ru2;
    float z  = U.zs * u;
    float z2 = z * z, z4 = z2 * z2;
    float lg = __logf(z);
    float t4 = c.q4 + c.cf4 * lg;
    float fz = 1.f + z * (c.q1 + z * (c.q2 + z * (c.q3 + z * t4)));
    float s  = 1.f + z * (c.e1 + z * (c.e2 + z * (c.e3 + z * c.e4)));
    float P  = 1.f + z * (c.b0 + z * (c.b1 + z * c.p3));
    float dP = c.b0 + z * (2.f * c.b1 + z * (3.f * c.p3));
    float D  = 1.f - z4;
    float rsqD = frsq(D);
    float rcpD = rsqD * rsqD;
    float rcpP = frcp(P);
    float zdgg = 2.f * z * dP * rcpP + 4.f * z4 * rcpD;   // z dg / g
    float F4 = fz * U.rfs * ru4;                          // r4 * f/fs
    float S4 = s  * U.rfs * ru4;
    float den = fmaxf(F4 - 1.f, EPSF);
    float rs  = frsq(den);
    float sqg = P * rsqD;
    float t1  = sqg * rs;
    iL = t1 * y;
    float t = F4 * (U.A4 + zdgg) + 4.f * S4 - 2.f - zdgg;
    float rs2 = rs * rs;
    iD = t * (2.f * y) * (t1 * rs2);                      // sqrt(1-z/zs) = y
}

__device__ __forceinline__ float point_Vc(const Co& c, const Uni& U,
                                          float y, float u) {
    float u2  = u * u;
    float u4  = u2 * u2;
    float ru2 = frcp(u2);
    float z  = U.zs * u;
    float z2 = z * z, z4 = z2 * z2;
    float lg = __logf(z);
    float t4 = c.q4 + c.cf4 * lg;
    float fz = 1.f + z * (c.q1 + z * (c.q2 + z * (c.q3 + z * t4)));
    float P  = 1.f + z * (c.b0 + z * (c.b1 + z * c.p3));
    float D  = 1.f - z4;
    float rsqD = frsq(D);
    float rcpD = rsqD * rsqD;
    float fg = fz * P * P * rcpD;
    float sqfg = fsqrt(fmaxf(fg, EPSF));
    float rfz = frcp(fz);
    float arg = fmaxf(1.f - u4 * U.fs * rfz, EPSF);
    float t = frsq(arg) - 1.f;
    return sqfg * ru2 * t * y;
}

__device__ __forceinline__ float point_Vd(const Co& c, const Uni& U, float y2) {
    float z  = 1.f - (1.f - U.zs) * y2;
    float z2 = z * z, z4 = z2 * z2;
    float lg = __logf(z);
    float t4 = c.q4 + c.cf4 * lg;
    float fz = 1.f + z * (c.q1 + z * (c.q2 + z * (c.q3 + z * t4)));
    float P  = 1.f + z * (c.b0 + z * (c.b1 + z * c.p3));
    float D  = 1.f - z4;
    float rsqD = frsq(D);
    float fg = fz * P * P * (rsqD * rsqD);
    float sq = fsqrt(fmaxf(fg, EPSF));
    float rz = frcp(z);
    return sq * rz * rz;
}

__device__ __forceinline__ float trapz_ext(float S, float i0, float i1, float iN) {
    float slope = (i1 - i0) * frcp(DYF);
    float v0 = i0 - slope * 0.001f;
    float yLast = 0.001f + 999.f * DYF;
    return DYF * (S - 0.5f * (i0 + iN))
         + 0.5f * (v0 + i0) * 0.001f
         + 0.5f * iN * (1.f - yLast);
}

__device__ __forceinline__ float trapz_d(float S, float q0, float qN) {
    return 0.5f * (1.f + q0) * 0.001f + DY2F * (S - 0.5f * (q0 + qN));
}

// ---------------------------------------------------------------------------
// Wave-local quadratures (16 points/lane) for the solve path.
// ---------------------------------------------------------------------------
__device__ __forceinline__ void wave_LdL(const Co& c, const Uni& U, int lane,
                                         float& Lout, float& dLout) {
    float sL = 0.f, sD = 0.f, l0 = 0.f, d0 = 0.f, lN = 0.f, dN = 0.f;
#pragma unroll
    for (int k = 0; k < 16; ++k) {
        if (k < 15 || lane < 40) {
            int j = lane + 64 * k;
            float y = fmaf((float)j, DYF, 0.001f);
            float u = 1.f - y * y;
            float iL, iD;
            point_LdL(c, U, y, u, iL, iD);
            sL += iL; sD += iD;
            if (k == 0)  { l0 = iL; d0 = iD; }
            if (k == 15) { lN = iL; dN = iD; }
        }
    }
#pragma unroll
    for (int o = 32; o > 0; o >>= 1) {
        sL += __shfl_xor(sL, o, 64);
        sD += __shfl_xor(sD, o, 64);
    }
    float i0 = __shfl(l0, 0, 64), i1 = __shfl(l0, 1, 64), iN = __shfl(lN, 39, 64);
    float e0 = __shfl(d0, 0, 64), e1 = __shfl(d0, 1, 64), eN = __shfl(dN, 39, 64);
    Lout  = 4.f * U.zs * trapz_ext(sL, i0, i1, iN) / PI_F;
    dLout = trapz_ext(sD, e0, e1, eN) / PI_F;
}

__device__ __forceinline__ float wave_V(const Co& c, const Uni& U, int lane) {
    float sc = 0.f, sd = 0.f, c0 = 0.f, cN = 0.f, q0 = 0.f, qN = 0.f;
#pragma unroll
    for (int k = 0; k < 16; ++k) {
        if (k < 15 || lane < 40) {
            int j = lane + 64 * k;
            float y = fmaf((float)j, DYF, 0.001f);
            float u = 1.f - y * y;
            float vc = point_Vc(c, U, y, u);
            float y2 = fmaf((float)j, DY2F, 0.001f);
            float vd = point_Vd(c, U, y2);
            sc += vc; sd += vd;
            if (k == 0)  { c0 = vc; q0 = vd; }
            if (k == 15) { cN = vc; qN = vd; }
        }
    }
#pragma unroll
    for (int o = 32; o > 0; o >>= 1) {
        sc += __shfl_xor(sc, o, 64);
        sd += __shfl_xor(sd, o, 64);
    }
    float i0 = __shfl(c0, 0, 64), i1 = __shfl(c0, 1, 64), iN = __shfl(cN, 39, 64);
    float p0 = __shfl(q0, 0, 64), pN = __shfl(qN, 39, 64);
    float Vc = c.coef * PI_F * 4.f * trapz_ext(sc, i0, i1, iN) * frcp(U.zs);
    float Vd = c.coef * PI_F * 2.f * (1.f - U.zs) * trapz_d(sd, p0, pN);
    return Vc - Vd;
}

// ---------------------------------------------------------------------------
// Kernel A: parallel grid evaluation.  Wave i<NG computes dL AND L at z_i
// (iL was already computed and thrown away in R13 — now stored for the
// newton inverse-table init); wave i>=NG computes V.
// ---------------------------------------------------------------------------
__global__ __launch_bounds__(256) void grid_eval_kernel(
        const float* a, const float* b, const float* lc, float* ws) {
    int wid = (blockIdx.x * blockDim.x + threadIdx.x) >> 6;
    int lane = threadIdx.x & 63;
    if (wid >= 2 * NG) return;
    Co c = make_co(a, b, lc);
    int i = (wid < NG) ? wid : wid - NG;
    float zq = fmaf((float)i + 0.5f, HG, 0.001f);
    Uni U = make_uni(c, zq);
    if (wid < NG) {
        float Lv, dLv;
        wave_LdL(c, U, lane, Lv, dLv);
        if (lane == 0) { ws[16 + i] = dLv; ws[16 + 2 * NG + i] = Lv; }
    } else {
        float v = wave_V(c, U, lane);
        if (lane == 0) ws[16 + NG + i] = v;
    }
}

// ---------------------------------------------------------------------------
// Kernel B: crossing scan + 1 false-position round (bracket h=4.9e-4,
// transversal crossing -> 1 round + final secant ~1e-7 err << 2e-5 budget)
// + fused final L(zs_max), L(zs_crit).  Stores the L-table bound ws[4]=idl.
// ---------------------------------------------------------------------------
__global__ __launch_bounds__(1024) void refine_kernel(
        const float* a, const float* b, const float* lc, float* ws) {
    __shared__ float pA[16], pB[16], spec[6];
    __shared__ int sdl, sv;
    Co c = make_co(a, b, lc);
    int t = threadIdx.x;
    int lane = t & 63, w = t >> 6;
    const float* dLbuf = ws + 16;
    const float* Vbuf  = ws + 16 + NG;

    if (t == 0) { sdl = 1 << 30; sv = 1 << 30; }
    __syncthreads();
#pragma unroll
    for (int r = 0; r < NG / 1024; ++r) {
        int i = t + 1024 * r;
        float dcur = dLbuf[i];
        float dprev = (i > 0) ? dLbuf[i - 1] : 1.f;     // dL(lo) >= 0 invariant
        if (dcur < 0.f && dprev >= 0.f) atomicMin(&sdl, i);
        float vcur = Vbuf[i];
        float vprev = (i > 0) ? Vbuf[i - 1] : -1.f;     // V(lo) <= 0 invariant
        if (vcur > 0.f && vprev <= 0.f) atomicMin(&sv, i);
    }
    __syncthreads();
    int idl = sdl, iv = sv;

    float zs_max;
    if (idl >= NG) {
        zs_max = 0.999f;
    } else {
        float zhi = fmaf((float)idl + 0.5f, HG, 0.001f);
        float zlo = (idl > 0) ? zhi - HG : 0.001f;
        zs_max = 0.5f * (zlo + zhi);
    }

    float zs_crit;
    bool refine = false;
    float zlo = 0.001f, zhi = zs_max, vlo = -1.f, vhi = 1.f;
    if (iv >= NG) {
        zs_crit = zs_max;
    } else {
        zhi = fmaf((float)iv + 0.5f, HG, 0.001f);
        vhi = Vbuf[iv];
        if (iv > 0) { zlo = zhi - HG; vlo = Vbuf[iv - 1]; }
        else        { zlo = 0.001f;   vlo = -1.f; }
        if (zhi > zs_max) {
            zs_crit = zs_max;
        } else {
            refine = true;
            zs_crit = 0.5f * (zlo + zhi);
        }
    }
    if (refine) {
        bool act = (t < MQ);
        float y = fmaf((float)t, DYF, 0.001f);
        float u = 1.f - y * y;
        float y2 = fmaf((float)t, DY2F, 0.001f);
        for (int round = 0; round < 1; ++round) {
            float den = vhi - vlo;
            float znew = zlo - vlo * (zhi - zlo) * frcp(den);
            if (!(znew > zlo && znew < zhi)) znew = 0.5f * (zlo + zhi);
            Uni U = make_uni(c, znew);
            float vc = 0.f, vd = 0.f;
            if (act) { vc = point_Vc(c, U, y, u); vd = point_Vd(c, U, y2); }
            float sc = vc, sd = vd;
#pragma unroll
            for (int o = 32; o > 0; o >>= 1) {
                sc += __shfl_xor(sc, o, 64);
                sd += __shfl_xor(sd, o, 64);
            }
            if (lane == 0) { pA[w] = sc; pB[w] = sd; }
            if (t == 0)      { spec[0] = vc; spec[3] = vd; }
            if (t == 1)      { spec[1] = vc; }
            if (t == MQ - 1) { spec[2] = vc; spec[4] = vd; }
            __syncthreads();
            float Sc = 0.f, Sd = 0.f;
#pragma unroll
            for (int i = 0; i < 16; ++i) { Sc += pA[i]; Sd += pB[i]; }
            float Vc = c.coef * PI_F * 4.f * trapz_ext(Sc, spec[0], spec[1], spec[2]) * frcp(znew);
            float Vd = c.coef * PI_F * 2.f * (1.f - znew) * trapz_d(Sd, spec[3], spec[4]);
            float Vnew = Vc - Vd;
            __syncthreads();
            if (Vnew > 0.f) { zhi = znew; vhi = Vnew; }
            else            { zlo = znew; vlo = Vnew; }
        }
        float den = vhi - vlo;
        zs_crit = zlo - vlo * (zhi - zlo) * frcp(den);
        if (!(zs_crit > zlo && zs_crit < zhi)) zs_crit = 0.5f * (zlo + zhi);
    }

    {
        bool act = (t < MQ);
        float y = fmaf((float)t, DYF, 0.001f);
        float u = 1.f - y * y;
        Uni Um = make_uni(c, zs_max);
        Uni Uc = make_uni(c, zs_crit);
        float lm = 0.f, lcv = 0.f;
        if (act) {
            float d1, d2;
            point_LdL(c, Um, y, u, lm, d1);
            point_LdL(c, Uc, y, u, lcv, d2);
        }
        float sm = lm, sc2 = lcv;
#pragma unroll
        for (int o = 32; o > 0; o >>= 1) {
            sm  += __shfl_xor(sm, o, 64);
            sc2 += __shfl_xor(sc2, o, 64);
        }
        if (lane == 0) { pA[w] = sm; pB[w] = sc2; }
        if (t == 0)      { spec[0] = lm; spec[3] = lcv; }
        if (t == 1)      { spec[1] = lm; spec[4] = lcv; }
        if (t == MQ - 1) { spec[2] = lm; spec[5] = lcv; }
        __syncthreads();
        if (t == 0) {
            float Sm = 0.f, Sc2 = 0.f;
#pragma unroll
            for (int i = 0; i < 16; ++i) { Sm += pA[i]; Sc2 += pB[i]; }
            float L_max  = 4.f * zs_max  * trapz_ext(Sm,  spec[0], spec[1], spec[2]) / PI_F;
            float L_crit = 4.f * zs_crit * trapz_ext(Sc2, spec[3], spec[4], spec[5]) / PI_F;
            ws[0] = zs_max; ws[1] = L_max; ws[2] = zs_crit; ws[3] = L_crit;
            ws[4] = (float)((idl < NG) ? idl : NG);   // L-table monotone bound
        }
    }
}

// ---------------------------------------------------------------------------
// Kernel C: per-element Newton + V, 128 threads (2 waves) / element.
// R14: init by INVERTING THE L-TABLE (binary search + linear interp; the
// grid kernel now stores L at 2048 points).  Init L-error ~ h^2 L''/8 ~1e-6
// -> most elements hit the residual exit in 1-2 steps (R13 was ~4-5; kernel
// is total-work-bound so average steps is the lever).  Cap 7 -> 6.
// j = t + 128k, k<8 (k==7 -> t<104); j==0,1 -> t=0,1 (k=0); j==999 -> t=103 (k=7).
// ---------------------------------------------------------------------------
__global__ __launch_bounds__(128) void newton_v_kernel(
        const float* Ls, const float* a, const float* b, const float* lc,
        const float* ws, float* out, int B) {
    __shared__ float red[2][2][2];   // [parity][{L,D}][wave]
    __shared__ float sp[2][6];       // [parity][i0,i1,iN, d0,d1,dN]
    int wid = blockIdx.x;
    int t = threadIdx.x;
    int lane = t & 63, w = t >> 6;
    if (wid >= B) return;

    float L_crit = ws[3];
    float Lq = Ls[wid];
    if (!(Lq < L_crit)) {              // invalid row: exact 0, skip all work
        if (t == 0) out[wid] = 0.f;
        return;
    }

    Co c = make_co(a, b, lc);
    float zs_crit = ws[2];
    float L_eff = Lq;

    // --- inverse-table init ---
    const float* Lbuf = ws + 16 + 2 * NG;
    int bound = (int)ws[4];            // L monotone increasing on [0, bound)
    float zs;
    if (bound >= 2) {
        // largest idx in [0, bound) with L[idx] < L_eff  (block-uniform search)
        int lo = -1, hi = bound - 1;
        while (hi > lo) {
            int mid = (lo + hi + 1) >> 1;
            if (Lbuf[mid] < L_eff) lo = mid; else hi = mid - 1;
        }
        if (lo < 0) {
            float z0 = 0.001f + 0.5f * HG;
            zs = z0 * L_eff * frcp(fmaxf(Lbuf[0], 1e-20f));
        } else if (lo >= bound - 1) {
            zs = L_eff * frcp(L_crit) * zs_crit;   // chord fallback
        } else {
            float zl = fmaf((float)lo + 0.5f, HG, 0.001f);
            float Ll = Lbuf[lo], Lh = Lbuf[lo + 1];
            zs = zl + (L_eff - Ll) * HG * frcp(fmaxf(Lh - Ll, 1e-20f));
        }
    } else {
        zs = L_eff * frcp(L_crit) * zs_crit;       // chord fallback
    }
    zs = fminf(fmaxf(zs, 1e-4f), 0.9995f);

    float zs_prev = -1.f;
    float best_res = 1e30f, zs_best = zs;
    int stall = 0;
    int par = 0;

    for (int step = 0; step < 6; ++step) {
        Uni U = make_uni(c, zs);
        float sL = 0.f, sD = 0.f, l0 = 0.f, d0 = 0.f, l1 = 0.f, d1 = 0.f,
              lN = 0.f, dN = 0.f;
#pragma unroll
        for (int k = 0; k < 8; ++k) {
            if (k < 7 || t < 104) {        // j < 1000; constant-true for k<7
                int j = t + 128 * k;
                float y = fmaf((float)j, DYF, 0.001f);
                float u = 1.f - y * y;
                float iL, iD;
                point_LdL(c, U, y, u, iL, iD);
                sL += iL; sD += iD;
                if (k == 0) {
                    if (t == 0) { l0 = iL; d0 = iD; }
                    if (t == 1) { l1 = iL; d1 = iD; }
                }
                if (k == 7 && t == 103) { lN = iL; dN = iD; }
            }
        }
#pragma unroll
        for (int o = 32; o > 0; o >>= 1) {
            sL += __shfl_xor(sL, o, 64);
            sD += __shfl_xor(sD, o, 64);
        }
        if (lane == 0) { red[par][0][w] = sL; red[par][1][w] = sD; }
        if (t == 0)   { sp[par][0] = l0; sp[par][3] = d0; }
        if (t == 1)   { sp[par][1] = l1; sp[par][4] = d1; }
        if (t == 103) { sp[par][2] = lN; sp[par][5] = dN; }
        __syncthreads();
        float SL = red[par][0][0] + red[par][0][1];
        float SD = red[par][1][0] + red[par][1][1];
        float i0 = sp[par][0], i1 = sp[par][1], iN = sp[par][2];
        float e0 = sp[par][3], e1 = sp[par][4], eN = sp[par][5];
        par ^= 1;                         // next step writes the other buffer
        float Lz = 4.f * zs * trapz_ext(SL, i0, i1, iN) / PI_F;
        float dL = trapz_ext(SD, e0, e1, eN) / PI_F;
        float res = fabsf(Lz - L_eff);
        if (res <= fmaf(L_eff, 1e-5f, 1e-8f)) break;
        if (res < 0.25f * best_res) {
            best_res = res; zs_best = zs;
            stall = 0;
        } else {
            if (res < best_res) { best_res = res; zs_best = zs; }
            if (++stall >= 2) { zs = zs_best; break; }
        }
        float nzs = fminf(fmaxf(zs - (Lz - L_eff) * frcp(dL), 1e-4f), 0.9995f);
        if (fabsf(nzs - zs) <= fmaf(zs, 1e-5f, 1e-7f)) { zs = nzs; break; }
        if (nzs == zs_prev) break;
        zs_prev = zs;
        zs = nzs;
    }

    // V(zs): same 2-wave split; reuse parity buffers (barrier inside).
    Uni U = make_uni(c, zs);
    float sc = 0.f, sd = 0.f, c0 = 0.f, c1v = 0.f, cN = 0.f, q0 = 0.f, qN = 0.f;
#pragma unroll
    for (int k = 0; k < 8; ++k) {
        if (k < 7 || t < 104) {
            int j = t + 128 * k;
            float y = fmaf((float)j, DYF, 0.001f);
            float u = 1.f - y * y;
            float vc = point_Vc(c, U, y, u);
            float y2 = fmaf((float)j, DY2F, 0.001f);
            float vd = point_Vd(c, U, y2);
            sc += vc; sd += vd;
            if (k == 0) {
                if (t == 0) { c0 = vc; q0 = vd; }
                if (t == 1) { c1v = vc; }
            }
            if (k == 7 && t == 103) { cN = vc; qN = vd; }
        }
    }
#pragma unroll
    for (int o = 32; o > 0; o >>= 1) {
        sc += __shfl_xor(sc, o, 64);
        sd += __shfl_xor(sd, o, 64);
    }
    if (lane == 0) { red[par][0][w] = sc; red[par][1][w] = sd; }
    if (t == 0)   { sp[par][0] = c0; sp[par][3] = q0; }
    if (t == 1)   { sp[par][1] = c1v; }
    if (t == 103) { sp[par][2] = cN; sp[par][4] = qN; }
    __syncthreads();
    if (t == 0) {
        float Sc = red[par][0][0] + red[par][0][1];
        float Sd = red[par][1][0] + red[par][1][1];
        float Vc = c.coef * PI_F * 4.f * trapz_ext(Sc, sp[par][0], sp[par][1], sp[par][2]) * frcp(zs);
        float Vd = c.coef * PI_F * 2.f * (1.f - zs) * trapz_d(Sd, sp[par][3], sp[par][4]);
        out[wid] = Vc - Vd;
    }
}

// ---------------------------------------------------------------------------
extern "C" void kernel_launch(void* const* d_in, const int* in_sizes, int n_in,
                              void* d_out, int out_size, void* d_ws, size_t ws_size,
                              hipStream_t stream) {
    const float* Ls = (const float*)d_in[0];
    const float* a  = (const float*)d_in[1];
    const float* b  = (const float*)d_in[2];
    const float* lc = (const float*)d_in[3];
    float* out = (float*)d_out;
    float* ws  = (float*)d_ws;
    int B = in_sizes[0];

    int blocksA = (2 * NG * 64) / 256;       // 4096 waves
    grid_eval_kernel<<<blocksA, 256, 0, stream>>>(a, b, lc, ws);
    refine_kernel<<<1, 1024, 0, stream>>>(a, b, lc, ws);

    newton_v_kernel<<<B, 128, 0, stream>>>(Ls, a, b, lc, ws, out, B);
}

// Round 16
// 97.262 us; speedup vs baseline: 1.8092x; 1.1629x over previous
//
#include <hip/hip_runtime.h>
#include <math.h>

#define MQ 1000
#define PI_F 3.14159265358979323846f
#define EPSF 1e-12f
#define DYF  ((float)(0.998/999.0))   // main y-grid step
#define DY2F ((float)(0.999/999.0))   // disconnected y2-grid step (= 0.001)
#define NG   2048                     // scan-grid points per function
#define HG   (0.998f / (float)NG)     // scan-grid step

// fast HW approx ops (v_rcp_f32 / v_rsq_f32 / v_sqrt_f32, ~1 ulp)
__device__ __forceinline__ float frcp(float x)  { return __builtin_amdgcn_rcpf(x); }
__device__ __forceinline__ float frsq(float x)  { return __builtin_amdgcn_rsqf(x); }
__device__ __forceinline__ float fsqrt(float x) { return __builtin_amdgcn_sqrtf(x); }

// ws layout: [0]=L_crit [1]=bound (float)
//            [16 .. 16+NG)        = dL grid
//            [16+NG .. 16+2NG)    = V grid
//            [16+2NG .. 16+3NG)   = L grid (monotone for z < zs_max)
//            grid z_i = 0.001 + (i+0.5)*HG

// ---------------------------------------------------------------------------
struct Co {
    float q1, q2, q3, q4, cf4;
    float e1, e2, e3, e4;
    float b0, b1, p3;
    float coef;
};

__device__ __forceinline__ Co make_co(const float* a, const float* b, const float* lc) {
    Co c;
    float a0 = a[0], a1 = a[1];
    float cf1 = -8.f * a0 / 3.f;
    float cf2 = -2.f * (2.f * a1 + a0 * a0);
    float cf3 = -8.f * a0 * a1;
    c.cf4 = -4.f * a1 * a1;
    c.q1 = -cf1; c.q2 = -cf2; c.q3 = -cf3; c.q4 = cf1 + cf2 + cf3 - 1.f;
    c.e1 = 2.f * a0;
    c.e2 = 2.f * a1 + a0 * a0;
    c.e3 = 2.f * a0 * a1;
    c.e4 = a1 * a1;
    c.b0 = b[0]; c.b1 = b[1];
    c.p3 = a0 + a1 - b[0] - b[1];
    c.coef = expf(lc[0]);
    return c;
}

struct Uni { float zs, fs, rfs, A4; };

__device__ __forceinline__ Uni make_uni(const Co& c, float zs) {
    Uni U; U.zs = zs;
    float z = zs;
    float lg = __logf(z);
    float t4 = c.q4 + c.cf4 * lg;
    float fz = 1.f + z * (c.q1 + z * (c.q2 + z * (c.q3 + z * t4)));
    float s  = 1.f + z * (c.e1 + z * (c.e2 + z * (c.e3 + z * c.e4)));
    U.fs = fz;
    U.rfs = frcp(fz);
    float dfs = 4.f * (fz - s) * frcp(z);
    U.A4 = zs * dfs * U.rfs - 2.f;     // (zs dfs/fs + 2) - 4
    return U;
}

__device__ __forceinline__ void point_LdL(const Co& c, const Uni& U,
                                          float y, float u,
                                          float& iL, float& iD) {
    float u2  = u * u;
    float ru2 = frcp(u2);
    float ru4 = ru2 * ru2;
    float z  = U.zs * u;
    float z2 = z * z, z4 = z2 * z2;
    float lg = __logf(z);
    float t4 = c.q4 + c.cf4 * lg;
    float fz = 1.f + z * (c.q1 + z * (c.q2 + z * (c.q3 + z * t4)));
    float s  = 1.f + z * (c.e1 + z * (c.e2 + z * (c.e3 + z * c.e4)));
    float P  = 1.f + z * (c.b0 + z * (c.b1 + z * c.p3));
    float dP = c.b0 + z * (2.f * c.b1 + z * (3.f * c.p3));
    float D  = 1.f - z4;
    float rsqD = frsq(D);
    float rcpD = rsqD * rsqD;
    float rcpP = frcp(P);
    float zdgg = 2.f * z * dP * rcpP + 4.f * z4 * rcpD;   // z dg / g
    float F4 = fz * U.rfs * ru4;                          // r4 * f/fs
    float S4 = s  * U.rfs * ru4;
    float den = fmaxf(F4 - 1.f, EPSF);
    float rs  = frsq(den);
    float sqg = P * rsqD;
    float t1  = sqg * rs;
    iL = t1 * y;
    float t = F4 * (U.A4 + zdgg) + 4.f * S4 - 2.f - zdgg;
    float rs2 = rs * rs;
    iD = t * (2.f * y) * (t1 * rs2);                      // sqrt(1-z/zs) = y
}

__device__ __forceinline__ float point_Vc(const Co& c, const Uni& U,
                                          float y, float u) {
    float u2  = u * u;
    float u4  = u2 * u2;
    float ru2 = frcp(u2);
    float z  = U.zs * u;
    float z2 = z * z, z4 = z2 * z2;
    float lg = __logf(z);
    float t4 = c.q4 + c.cf4 * lg;
    float fz = 1.f + z * (c.q1 + z * (c.q2 + z * (c.q3 + z * t4)));
    float P  = 1.f + z * (c.b0 + z * (c.b1 + z * c.p3));
    float D  = 1.f - z4;
    float rsqD = frsq(D);
    float rcpD = rsqD * rsqD;
    float fg = fz * P * P * rcpD;
    float sqfg = fsqrt(fmaxf(fg, EPSF));
    float rfz = frcp(fz);
    float arg = fmaxf(1.f - u4 * U.fs * rfz, EPSF);
    float t = frsq(arg) - 1.f;
    return sqfg * ru2 * t * y;
}

__device__ __forceinline__ float point_Vd(const Co& c, const Uni& U, float y2) {
    float z  = 1.f - (1.f - U.zs) * y2;
    float z2 = z * z, z4 = z2 * z2;
    float lg = __logf(z);
    float t4 = c.q4 + c.cf4 * lg;
    float fz = 1.f + z * (c.q1 + z * (c.q2 + z * (c.q3 + z * t4)));
    float P  = 1.f + z * (c.b0 + z * (c.b1 + z * c.p3));
    float D  = 1.f - z4;
    float rsqD = frsq(D);
    float fg = fz * P * P * (rsqD * rsqD);
    float sq = fsqrt(fmaxf(fg, EPSF));
    float rz = frcp(z);
    return sq * rz * rz;
}

__device__ __forceinline__ float trapz_ext(float S, float i0, float i1, float iN) {
    float slope = (i1 - i0) * frcp(DYF);
    float v0 = i0 - slope * 0.001f;
    float yLast = 0.001f + 999.f * DYF;
    return DYF * (S - 0.5f * (i0 + iN))
         + 0.5f * (v0 + i0) * 0.001f
         + 0.5f * iN * (1.f - yLast);
}

__device__ __forceinline__ float trapz_d(float S, float q0, float qN) {
    return 0.5f * (1.f + q0) * 0.001f + DY2F * (S - 0.5f * (q0 + qN));
}

// ---------------------------------------------------------------------------
// Wave-local quadratures (16 points/lane; j==0,1 -> k=0 lanes 0,1; j==999 ->
// k=15 lane 39).  All lanes return the same value.
// ---------------------------------------------------------------------------
__device__ __forceinline__ void wave_LdL(const Co& c, const Uni& U, int lane,
                                         float& Lout, float& dLout) {
    float sL = 0.f, sD = 0.f, l0 = 0.f, d0 = 0.f, lN = 0.f, dN = 0.f;
#pragma unroll
    for (int k = 0; k < 16; ++k) {
        if (k < 15 || lane < 40) {
            int j = lane + 64 * k;
            float y = fmaf((float)j, DYF, 0.001f);
            float u = 1.f - y * y;
            float iL, iD;
            point_LdL(c, U, y, u, iL, iD);
            sL += iL; sD += iD;
            if (k == 0)  { l0 = iL; d0 = iD; }
            if (k == 15) { lN = iL; dN = iD; }
        }
    }
#pragma unroll
    for (int o = 32; o > 0; o >>= 1) {
        sL += __shfl_xor(sL, o, 64);
        sD += __shfl_xor(sD, o, 64);
    }
    float i0 = __shfl(l0, 0, 64), i1 = __shfl(l0, 1, 64), iN = __shfl(lN, 39, 64);
    float e0 = __shfl(d0, 0, 64), e1 = __shfl(d0, 1, 64), eN = __shfl(dN, 39, 64);
    Lout  = 4.f * U.zs * trapz_ext(sL, i0, i1, iN) / PI_F;
    dLout = trapz_ext(sD, e0, e1, eN) / PI_F;
}

__device__ __forceinline__ float wave_V(const Co& c, const Uni& U, int lane) {
    float sc = 0.f, sd = 0.f, c0 = 0.f, cN = 0.f, q0 = 0.f, qN = 0.f;
#pragma unroll
    for (int k = 0; k < 16; ++k) {
        if (k < 15 || lane < 40) {
            int j = lane + 64 * k;
            float y = fmaf((float)j, DYF, 0.001f);
            float u = 1.f - y * y;
            float vc = point_Vc(c, U, y, u);
            float y2 = fmaf((float)j, DY2F, 0.001f);
            float vd = point_Vd(c, U, y2);
            sc += vc; sd += vd;
            if (k == 0)  { c0 = vc; q0 = vd; }
            if (k == 15) { cN = vc; qN = vd; }
        }
    }
#pragma unroll
    for (int o = 32; o > 0; o >>= 1) {
        sc += __shfl_xor(sc, o, 64);
        sd += __shfl_xor(sd, o, 64);
    }
    float i0 = __shfl(c0, 0, 64), i1 = __shfl(c0, 1, 64), iN = __shfl(cN, 39, 64);
    float p0 = __shfl(q0, 0, 64), pN = __shfl(qN, 39, 64);
    float Vc = c.coef * PI_F * 4.f * trapz_ext(sc, i0, i1, iN) * frcp(U.zs);
    float Vd = c.coef * PI_F * 2.f * (1.f - U.zs) * trapz_d(sd, p0, pN);
    return Vc - Vd;
}

// ---------------------------------------------------------------------------
// Kernel A: parallel grid evaluation (unchanged).  Wave i<NG computes dL and
// L at z_i; wave i>=NG computes V at z_{i-NG}.
// ---------------------------------------------------------------------------
__global__ __launch_bounds__(256) void grid_eval_kernel(
        const float* a, const float* b, const float* lc, float* ws) {
    int wid = (blockIdx.x * blockDim.x + threadIdx.x) >> 6;
    int lane = threadIdx.x & 63;
    if (wid >= 2 * NG) return;
    Co c = make_co(a, b, lc);
    int i = (wid < NG) ? wid : wid - NG;
    float zq = fmaf((float)i + 0.5f, HG, 0.001f);
    Uni U = make_uni(c, zq);
    if (wid < NG) {
        float Lv, dLv;
        wave_LdL(c, U, lane, Lv, dLv);
        if (lane == 0) { ws[16 + i] = dLv; ws[16 + 2 * NG + i] = Lv; }
    } else {
        float v = wave_V(c, U, lane);
        if (lane == 0) ws[16 + NG + i] = v;
    }
}

// ---------------------------------------------------------------------------
// Kernel B: 1-block table scan.  bound = first dL<0 (L monotone on [0,bound));
// zs_crit from the V sign crossing (secant on the bracket, transversal ->
// err ~1e-6); L_crit = L-table interp at zs_crit (V(zs_crit)=0, so the
// ~1e-6 shift of the validity cut is benign).  No quadratures here.
// ---------------------------------------------------------------------------
__global__ __launch_bounds__(256) void scan_kernel(float* ws) {
    __shared__ int sdl, sv;
    const float* dLbuf = ws + 16;
    const float* Vbuf  = ws + 16 + NG;
    const float* Lbuf  = ws + 16 + 2 * NG;
    int t = threadIdx.x;
    if (t == 0) { sdl = NG; sv = NG; }
    __syncthreads();
#pragma unroll
    for (int r = 0; r < NG / 256; ++r) {
        int i = t + 256 * r;
        float dcur = dLbuf[i];
        float dprev = (i > 0) ? dLbuf[i - 1] : 1.f;     // dL(lo) >= 0 invariant
        if (dcur < 0.f && dprev >= 0.f) atomicMin(&sdl, i);
        float vcur = Vbuf[i];
        float vprev = (i > 0) ? Vbuf[i - 1] : -1.f;     // V(lo) <= 0 invariant
        if (vcur > 0.f && vprev <= 0.f) atomicMin(&sv, i);
    }
    __syncthreads();
    if (t == 0) {
        int bound = sdl, iv = sv;
        float Lcrit;
        if (bound < 2) {
            Lcrit = -1.f;                       // degenerate: everything invalid
        } else if (iv >= NG || iv >= bound) {
            Lcrit = Lbuf[bound - 1];            // no crossing in range -> ~L_max
        } else if (iv == 0) {
            float z0 = 0.001f + 0.5f * HG;
            Lcrit = Lbuf[0] * 0.001f * frcp(z0);   // crossing at lo endpoint
        } else {
            float zhi = fmaf((float)iv + 0.5f, HG, 0.001f);
            float zlo = zhi - HG;
            float vhi = Vbuf[iv], vlo = Vbuf[iv - 1];
            float zc = zlo - vlo * (zhi - zlo) * frcp(fmaxf(vhi - vlo, 1e-30f));
            zc = fminf(fmaxf(zc, zlo), zhi);
            float tt = (zc - 0.001f) * frcp(HG) - 0.5f;
            int i0 = (int)tt;
            i0 = max(0, min(i0, bound - 2));
            float frac = fminf(fmaxf(tt - (float)i0, 0.f), 1.f);
            Lcrit = Lbuf[i0] + frac * (Lbuf[i0 + 1] - Lbuf[i0]);
        }
        ws[0] = Lcrit;
        ws[1] = (float)bound;
    }
}

// ---------------------------------------------------------------------------
// Kernel C: per-element — invert L-table, ONE clamped Newton correction,
// then exact V quadrature.  One wave per element, uniform 2 quadrature
// units per valid element (no loop, no stragglers).
//   - table monotone + exact-sample binary search => init err < h always;
//   - correction squares it (err ~<1e-6); delta clamped to +-2h, zs clipped
//     to [1e-4, 0.9995] (reproduces the reference's clamp for tiny L: both
//     settle exactly at 1e-4);
//   - V from the full quadrature at the corrected zs — no V interpolation
//     (R15's V-over-L chord failed: V ~ -C/zs is a steep hyperbola at
//     small L and extrapolation below the table blew up ~1e4).
// ---------------------------------------------------------------------------
__global__ __launch_bounds__(256) void elem_v_kernel(
        const float* Ls, const float* a, const float* b, const float* lc,
        const float* ws, float* out, int B) {
    int wid = (blockIdx.x * blockDim.x + threadIdx.x) >> 6;
    int lane = threadIdx.x & 63;
    if (wid >= B) return;

    float L_crit = ws[0];
    int bound = (int)ws[1];
    float Lq = Ls[wid];
    if (!(Lq < L_crit)) {              // invalid row: exact 0
        if (lane == 0) out[wid] = 0.f;
        return;
    }

    const float* Lbuf = ws + 16 + 2 * NG;
    // largest lo in [0, bound) with L[lo] < Lq  (wave-uniform search)
    int lo = -1, hi = bound - 1;
    while (hi > lo) {
        int mid = (lo + hi + 1) >> 1;
        if (Lbuf[mid] < Lq) lo = mid; else hi = mid - 1;
    }
    float zs;
    if (lo < 0) {
        // below first sample: L ~ linear through origin there
        float z0 = 0.001f + 0.5f * HG;
        zs = z0 * Lq * frcp(fmaxf(Lbuf[0], 1e-20f));
    } else {
        int seg = min(lo, bound - 2);          // lo==bound-1 -> extrapolate last seg
        float zl = fmaf((float)seg + 0.5f, HG, 0.001f);
        float Ll = Lbuf[seg], Lh = Lbuf[seg + 1];
        zs = zl + (Lq - Ll) * HG * frcp(fmaxf(Lh - Ll, 1e-20f));
    }
    zs = fminf(fmaxf(zs, 1e-4f), 0.9995f);

    Co c = make_co(a, b, lc);
    // one Newton correction from the exact quadrature
    Uni U = make_uni(c, zs);
    float Lz, dL;
    wave_LdL(c, U, lane, Lz, dL);
    float delta = (Lz - Lq) * frcp(dL);
    if (fabsf(delta) <= 2.f * HG)
        zs = fminf(fmaxf(zs - delta, 1e-4f), 0.9995f);

    // exact V at the corrected zs
    U = make_uni(c, zs);
    float V = wave_V(c, U, lane);
    if (lane == 0) out[wid] = V;
}

// ---------------------------------------------------------------------------
extern "C" void kernel_launch(void* const* d_in, const int* in_sizes, int n_in,
                              void* d_out, int out_size, void* d_ws, size_t ws_size,
                              hipStream_t stream) {
    const float* Ls = (const float*)d_in[0];
    const float* a  = (const float*)d_in[1];
    const float* b  = (const float*)d_in[2];
    const float* lc = (const float*)d_in[3];
    float* out = (float*)d_out;
    float* ws  = (float*)d_ws;
    int B = in_sizes[0];

    int blocksA = (2 * NG * 64) / 256;       // 4096 waves
    grid_eval_kernel<<<blocksA, 256, 0, stream>>>(a, b, lc, ws);
    scan_kernel<<<1, 256, 0, stream>>>(ws);

    int blocksC = (B + 3) / 4;               // 4 waves (elements) per block
    elem_v_kernel<<<blocksC, 256, 0, stream>>>(Ls, a, b, lc, ws, out, B);
}

// Round 17
// 94.637 us; speedup vs baseline: 1.8594x; 1.0277x over previous
//
#include <hip/hip_runtime.h>
#include <math.h>

#define MQ 1000
#define PI_F 3.14159265358979323846f
#define EPSF 1e-12f
#define DYF  ((float)(0.998/999.0))   // main y-grid step
#define DY2F ((float)(0.999/999.0))   // disconnected y2-grid step (= 0.001)
#define NG   2048                     // scan-grid points per function
#define HG   (0.998f / (float)NG)     // scan-grid step

// fast HW approx ops (v_rcp_f32 / v_rsq_f32 / v_sqrt_f32, ~1 ulp)
__device__ __forceinline__ float frcp(float x)  { return __builtin_amdgcn_rcpf(x); }
__device__ __forceinline__ float frsq(float x)  { return __builtin_amdgcn_rsqf(x); }
__device__ __forceinline__ float fsqrt(float x) { return __builtin_amdgcn_sqrtf(x); }

// ws layout: [0]=L_crit [1]=bound (float)
//            [16 .. 16+NG)        = dL grid
//            [16+NG .. 16+2NG)    = V grid
//            [16+2NG .. 16+3NG)   = L grid (monotone for z < zs_max)
//            grid z_i = 0.001 + (i+0.5)*HG

// ---------------------------------------------------------------------------
struct Co {
    float q1, q2, q3, q4, cf4;
    float e1, e2, e3, e4;
    float b0, b1, p3;
    float coef;
};

__device__ __forceinline__ Co make_co(const float* a, const float* b, const float* lc) {
    Co c;
    float a0 = a[0], a1 = a[1];
    float cf1 = -8.f * a0 / 3.f;
    float cf2 = -2.f * (2.f * a1 + a0 * a0);
    float cf3 = -8.f * a0 * a1;
    c.cf4 = -4.f * a1 * a1;
    c.q1 = -cf1; c.q2 = -cf2; c.q3 = -cf3; c.q4 = cf1 + cf2 + cf3 - 1.f;
    c.e1 = 2.f * a0;
    c.e2 = 2.f * a1 + a0 * a0;
    c.e3 = 2.f * a0 * a1;
    c.e4 = a1 * a1;
    c.b0 = b[0]; c.b1 = b[1];
    c.p3 = a0 + a1 - b[0] - b[1];
    c.coef = expf(lc[0]);
    return c;
}

struct Uni { float zs, fs, rfs, A4; };

__device__ __forceinline__ Uni make_uni(const Co& c, float zs) {
    Uni U; U.zs = zs;
    float z = zs;
    float lg = __logf(z);
    float t4 = c.q4 + c.cf4 * lg;
    float fz = 1.f + z * (c.q1 + z * (c.q2 + z * (c.q3 + z * t4)));
    float s  = 1.f + z * (c.e1 + z * (c.e2 + z * (c.e3 + z * c.e4)));
    U.fs = fz;
    U.rfs = frcp(fz);
    float dfs = 4.f * (fz - s) * frcp(z);
    U.A4 = zs * dfs * U.rfs - 2.f;     // (zs dfs/fs + 2) - 4
    return U;
}

__device__ __forceinline__ void point_LdL(const Co& c, const Uni& U,
                                          float y, float u,
                                          float& iL, float& iD) {
    float u2  = u * u;
    float ru2 = frcp(u2);
    float ru4 = ru2 * ru2;
    float z  = U.zs * u;
    float z2 = z * z, z4 = z2 * z2;
    float lg = __logf(z);
    float t4 = c.q4 + c.cf4 * lg;
    float fz = 1.f + z * (c.q1 + z * (c.q2 + z * (c.q3 + z * t4)));
    float s  = 1.f + z * (c.e1 + z * (c.e2 + z * (c.e3 + z * c.e4)));
    float P  = 1.f + z * (c.b0 + z * (c.b1 + z * c.p3));
    float dP = c.b0 + z * (2.f * c.b1 + z * (3.f * c.p3));
    float D  = 1.f - z4;
    float rsqD = frsq(D);
    float rcpD = rsqD * rsqD;
    float rcpP = frcp(P);
    float zdgg = 2.f * z * dP * rcpP + 4.f * z4 * rcpD;   // z dg / g
    float F4 = fz * U.rfs * ru4;                          // r4 * f/fs
    float S4 = s  * U.rfs * ru4;
    float den = fmaxf(F4 - 1.f, EPSF);
    float rs  = frsq(den);
    float sqg = P * rsqD;
    float t1  = sqg * rs;
    iL = t1 * y;
    float t = F4 * (U.A4 + zdgg) + 4.f * S4 - 2.f - zdgg;
    float rs2 = rs * rs;
    iD = t * (2.f * y) * (t1 * rs2);                      // sqrt(1-z/zs) = y
}

__device__ __forceinline__ float point_Vc(const Co& c, const Uni& U,
                                          float y, float u) {
    float u2  = u * u;
    float u4  = u2 * u2;
    float ru2 = frcp(u2);
    float z  = U.zs * u;
    float z2 = z * z, z4 = z2 * z2;
    float lg = __logf(z);
    float t4 = c.q4 + c.cf4 * lg;
    float fz = 1.f + z * (c.q1 + z * (c.q2 + z * (c.q3 + z * t4)));
    float P  = 1.f + z * (c.b0 + z * (c.b1 + z * c.p3));
    float D  = 1.f - z4;
    float rsqD = frsq(D);
    float rcpD = rsqD * rsqD;
    float fg = fz * P * P * rcpD;
    float sqfg = fsqrt(fmaxf(fg, EPSF));
    float rfz = frcp(fz);
    float arg = fmaxf(1.f - u4 * U.fs * rfz, EPSF);
    float t = frsq(arg) - 1.f;
    return sqfg * ru2 * t * y;
}

__device__ __forceinline__ float point_Vd(const Co& c, const Uni& U, float y2) {
    float z  = 1.f - (1.f - U.zs) * y2;
    float z2 = z * z, z4 = z2 * z2;
    float lg = __logf(z);
    float t4 = c.q4 + c.cf4 * lg;
    float fz = 1.f + z * (c.q1 + z * (c.q2 + z * (c.q3 + z * t4)));
    float P  = 1.f + z * (c.b0 + z * (c.b1 + z * c.p3));
    float D  = 1.f - z4;
    float rsqD = frsq(D);
    float fg = fz * P * P * (rsqD * rsqD);
    float sq = fsqrt(fmaxf(fg, EPSF));
    float rz = frcp(z);
    return sq * rz * rz;
}

__device__ __forceinline__ float trapz_ext(float S, float i0, float i1, float iN) {
    float slope = (i1 - i0) * frcp(DYF);
    float v0 = i0 - slope * 0.001f;
    float yLast = 0.001f + 999.f * DYF;
    return DYF * (S - 0.5f * (i0 + iN))
         + 0.5f * (v0 + i0) * 0.001f
         + 0.5f * iN * (1.f - yLast);
}

__device__ __forceinline__ float trapz_d(float S, float q0, float qN) {
    return 0.5f * (1.f + q0) * 0.001f + DY2F * (S - 0.5f * (q0 + qN));
}

// ---------------------------------------------------------------------------
// Kernel A: grid evaluation, 2 waves (128 threads) per grid point for
// latency hiding (R16 post-mortem: 1-wave kernels sit at ~35% VALUBusy —
// too few waves/SIMD to hide rcp/rsq/log chains).  Block i<NG: L and dL at
// z_i; block i>=NG: V at z_{i-NG}.  j = t + 128k; j=0,1 -> t=0,1 (k=0);
// j=999 -> t=103 (k=7).
// ---------------------------------------------------------------------------
__global__ __launch_bounds__(128) void grid_eval_kernel(
        const float* a, const float* b, const float* lc, float* ws) {
    __shared__ float red[4];
    __shared__ float spx[8];
    int bid = blockIdx.x;
    int t = threadIdx.x, lane = t & 63, w = t >> 6;
    Co c = make_co(a, b, lc);
    int i = (bid < NG) ? bid : bid - NG;
    float zq = fmaf((float)i + 0.5f, HG, 0.001f);
    Uni U = make_uni(c, zq);

    if (bid < NG) {
        float sL = 0.f, sD = 0.f, l0 = 0.f, d0 = 0.f, l1 = 0.f, d1 = 0.f,
              lN = 0.f, dN = 0.f;
#pragma unroll
        for (int k = 0; k < 8; ++k) {
            if (k < 7 || t < 104) {
                int j = t + 128 * k;
                float y = fmaf((float)j, DYF, 0.001f);
                float u = 1.f - y * y;
                float iL, iD;
                point_LdL(c, U, y, u, iL, iD);
                sL += iL; sD += iD;
                if (k == 0) {
                    if (t == 0) { l0 = iL; d0 = iD; }
                    if (t == 1) { l1 = iL; d1 = iD; }
                }
                if (k == 7 && t == 103) { lN = iL; dN = iD; }
            }
        }
#pragma unroll
        for (int o = 32; o > 0; o >>= 1) {
            sL += __shfl_xor(sL, o, 64);
            sD += __shfl_xor(sD, o, 64);
        }
        if (lane == 0) { red[w] = sL; red[2 + w] = sD; }
        if (t == 0)   { spx[0] = l0; spx[3] = d0; }
        if (t == 1)   { spx[1] = l1; spx[4] = d1; }
        if (t == 103) { spx[2] = lN; spx[5] = dN; }
        __syncthreads();
        if (t == 0) {
            float SL = red[0] + red[1], SD = red[2] + red[3];
            float Lv  = 4.f * zq * trapz_ext(SL, spx[0], spx[1], spx[2]) / PI_F;
            float dLv = trapz_ext(SD, spx[3], spx[4], spx[5]) / PI_F;
            ws[16 + i] = dLv;
            ws[16 + 2 * NG + i] = Lv;
        }
    } else {
        float sc = 0.f, sd = 0.f, c0 = 0.f, c1v = 0.f, cN = 0.f,
              q0 = 0.f, qN = 0.f;
#pragma unroll
        for (int k = 0; k < 8; ++k) {
            if (k < 7 || t < 104) {
                int j = t + 128 * k;
                float y = fmaf((float)j, DYF, 0.001f);
                float u = 1.f - y * y;
                float vc = point_Vc(c, U, y, u);
                float y2 = fmaf((float)j, DY2F, 0.001f);
                float vd = point_Vd(c, U, y2);
                sc += vc; sd += vd;
                if (k == 0) {
                    if (t == 0) { c0 = vc; q0 = vd; }
                    if (t == 1) { c1v = vc; }
                }
                if (k == 7 && t == 103) { cN = vc; qN = vd; }
            }
        }
#pragma unroll
        for (int o = 32; o > 0; o >>= 1) {
            sc += __shfl_xor(sc, o, 64);
            sd += __shfl_xor(sd, o, 64);
        }
        if (lane == 0) { red[w] = sc; red[2 + w] = sd; }
        if (t == 0)   { spx[0] = c0; spx[3] = q0; }
        if (t == 1)   { spx[1] = c1v; }
        if (t == 103) { spx[2] = cN; spx[4] = qN; }
        __syncthreads();
        if (t == 0) {
            float Sc = red[0] + red[1], Sd = red[2] + red[3];
            float Vc = c.coef * PI_F * 4.f * trapz_ext(Sc, spx[0], spx[1], spx[2]) * frcp(zq);
            float Vd = c.coef * PI_F * 2.f * (1.f - zq) * trapz_d(Sd, spx[3], spx[4]);
            ws[16 + NG + i] = Vc - Vd;
        }
    }
}

// ---------------------------------------------------------------------------
// Kernel B: 1-block table scan (unchanged from R16).
// ---------------------------------------------------------------------------
__global__ __launch_bounds__(256) void scan_kernel(float* ws) {
    __shared__ int sdl, sv;
    const float* dLbuf = ws + 16;
    const float* Vbuf  = ws + 16 + NG;
    const float* Lbuf  = ws + 16 + 2 * NG;
    int t = threadIdx.x;
    if (t == 0) { sdl = NG; sv = NG; }
    __syncthreads();
#pragma unroll
    for (int r = 0; r < NG / 256; ++r) {
        int i = t + 256 * r;
        float dcur = dLbuf[i];
        float dprev = (i > 0) ? dLbuf[i - 1] : 1.f;     // dL(lo) >= 0 invariant
        if (dcur < 0.f && dprev >= 0.f) atomicMin(&sdl, i);
        float vcur = Vbuf[i];
        float vprev = (i > 0) ? Vbuf[i - 1] : -1.f;     // V(lo) <= 0 invariant
        if (vcur > 0.f && vprev <= 0.f) atomicMin(&sv, i);
    }
    __syncthreads();
    if (t == 0) {
        int bound = sdl, iv = sv;
        float Lcrit;
        if (bound < 2) {
            Lcrit = -1.f;                       // degenerate: everything invalid
        } else if (iv >= NG || iv >= bound) {
            Lcrit = Lbuf[bound - 1];            // no crossing in range -> ~L_max
        } else if (iv == 0) {
            float z0 = 0.001f + 0.5f * HG;
            Lcrit = Lbuf[0] * 0.001f * frcp(z0);   // crossing at lo endpoint
        } else {
            float zhi = fmaf((float)iv + 0.5f, HG, 0.001f);
            float zlo = zhi - HG;
            float vhi = Vbuf[iv], vlo = Vbuf[iv - 1];
            float zc = zlo - vlo * (zhi - zlo) * frcp(fmaxf(vhi - vlo, 1e-30f));
            zc = fminf(fmaxf(zc, zlo), zhi);
            float tt = (zc - 0.001f) * frcp(HG) - 0.5f;
            int i0 = (int)tt;
            i0 = max(0, min(i0, bound - 2));
            float frac = fminf(fmaxf(tt - (float)i0, 0.f), 1.f);
            Lcrit = Lbuf[i0] + frac * (Lbuf[i0 + 1] - Lbuf[i0]);
        }
        ws[0] = Lcrit;
        ws[1] = (float)bound;
    }
}

// ---------------------------------------------------------------------------
// Kernel C: per-element — CUBIC-HERMITE inversion of the (L, dL) tables
// (no per-element L quadrature: Hermite error h^4|L''''|/384 ~ 1e-13, far
// below the tables' own f32 noise; 2 polynomial Newton iterations, ~50
// flops), then ONE exact V quadrature.  2 waves (128 threads) per element
// for latency hiding.  Uniform 1 quadrature unit per valid element.
// ---------------------------------------------------------------------------
__global__ __launch_bounds__(128) void elem_v_kernel(
        const float* Ls, const float* a, const float* b, const float* lc,
        const float* ws, float* out, int B) {
    __shared__ float red[4];
    __shared__ float spx[8];
    int wid = blockIdx.x;
    int t = threadIdx.x, lane = t & 63, w = t >> 6;
    if (wid >= B) return;

    float L_crit = ws[0];
    int bound = (int)ws[1];
    float Lq = Ls[wid];
    if (!(Lq < L_crit) || bound < 2) {   // invalid row: exact 0
        if (t == 0) out[wid] = 0.f;
        return;
    }

    const float* dLbuf = ws + 16;
    const float* Lbuf  = ws + 16 + 2 * NG;
    // largest lo in [0, bound) with L[lo] < Lq (block-uniform, redundant)
    int lo = -1, hi = bound - 1;
    while (hi > lo) {
        int mid = (lo + hi + 1) >> 1;
        if (Lbuf[mid] < Lq) lo = mid; else hi = mid - 1;
    }
    float zs;
    if (lo < 0) {
        // below first sample: L ~ linear through origin (rel err ~0.05*zs)
        float z0 = 0.001f + 0.5f * HG;
        zs = z0 * Lq * frcp(fmaxf(Lbuf[0], 1e-20f));
    } else {
        int seg = min(lo, bound - 2);
        float zl = fmaf((float)seg + 0.5f, HG, 0.001f);
        float Ll = Lbuf[seg],  Lh = Lbuf[seg + 1];
        float dl = dLbuf[seg] * HG, dh = dLbuf[seg + 1] * HG;  // d/ds scale
        float s = fminf(fmaxf((Lq - Ll) * frcp(fmaxf(Lh - Ll, 1e-20f)), 0.f), 1.f);
#pragma unroll
        for (int it = 0; it < 2; ++it) {
            float s2 = s * s, s3 = s2 * s;
            float H  = (2.f*s3 - 3.f*s2 + 1.f) * Ll + (s3 - 2.f*s2 + s) * dl
                     + (-2.f*s3 + 3.f*s2) * Lh + (s3 - s2) * dh;
            float Hp = (6.f*s2 - 6.f*s) * (Ll - Lh)
                     + (3.f*s2 - 4.f*s + 1.f) * dl + (3.f*s2 - 2.f*s) * dh;
            float step = (H - Lq) * frcp(Hp);
            if (fabsf(Hp) > 1e-20f) s = fminf(fmaxf(s - step, 0.f), 1.f);
        }
        zs = fmaf(s, HG, zl);
    }
    zs = fminf(fmaxf(zs, 1e-4f), 0.9995f);

    // exact V quadrature at zs (8 pts/lane x 2 waves)
    Co c = make_co(a, b, lc);
    Uni U = make_uni(c, zs);
    float sc = 0.f, sd = 0.f, c0 = 0.f, c1v = 0.f, cN = 0.f, q0 = 0.f, qN = 0.f;
#pragma unroll
    for (int k = 0; k < 8; ++k) {
        if (k < 7 || t < 104) {
            int j = t + 128 * k;
            float y = fmaf((float)j, DYF, 0.001f);
            float u = 1.f - y * y;
            float vc = point_Vc(c, U, y, u);
            float y2 = fmaf((float)j, DY2F, 0.001f);
            float vd = point_Vd(c, U, y2);
            sc += vc; sd += vd;
            if (k == 0) {
                if (t == 0) { c0 = vc; q0 = vd; }
                if (t == 1) { c1v = vc; }
            }
            if (k == 7 && t == 103) { cN = vc; qN = vd; }
        }
    }
#pragma unroll
    for (int o = 32; o > 0; o >>= 1) {
        sc += __shfl_xor(sc, o, 64);
        sd += __shfl_xor(sd, o, 64);
    }
    if (lane == 0) { red[w] = sc; red[2 + w] = sd; }
    if (t == 0)   { spx[0] = c0; spx[3] = q0; }
    if (t == 1)   { spx[1] = c1v; }
    if (t == 103) { spx[2] = cN; spx[4] = qN; }
    __syncthreads();
    if (t == 0) {
        float Sc = red[0] + red[1], Sd = red[2] + red[3];
        float Vc = c.coef * PI_F * 4.f * trapz_ext(Sc, spx[0], spx[1], spx[2]) * frcp(zs);
        float Vd = c.coef * PI_F * 2.f * (1.f - zs) * trapz_d(Sd, spx[3], spx[4]);
        out[wid] = Vc - Vd;
    }
}

// ---------------------------------------------------------------------------
extern "C" void kernel_launch(void* const* d_in, const int* in_sizes, int n_in,
                              void* d_out, int out_size, void* d_ws, size_t ws_size,
                              hipStream_t stream) {
    const float* Ls = (const float*)d_in[0];
    const float* a  = (const float*)d_in[1];
    const float* b  = (const float*)d_in[2];
    const float* lc = (const float*)d_in[3];
    float* out = (float*)d_out;
    float* ws  = (float*)d_ws;
    int B = in_sizes[0];

    grid_eval_kernel<<<2 * NG, 128, 0, stream>>>(a, b, lc, ws);
    scan_kernel<<<1, 256, 0, stream>>>(ws);
    elem_v_kernel<<<B, 128, 0, stream>>>(Ls, a, b, lc, ws, out, B);
}